// Round 1
// baseline (453.148 us; speedup 1.0000x reference)
//
#include <hip/hip_runtime.h>

// ---------------- problem constants ----------------
#define NEDGES   100000
#define NODE_DIM 128
#define CTX_DIM  256
#define OUT_DIM  256
#define IN_DIM   384
#define NCOEF    7

// kan_gemm2 tiling: K' = i*8 + slot, slot0=silu, slot1..7=spline c=slot-1
#define BM2      128
#define BK2      32            // 4 x-cols * 8 slots
#define NCH2     96            // IN_DIM / 4
#define THR2     512           // 8 waves

typedef __bf16 bf16x8 __attribute__((ext_vector_type(8)));
typedef float  f32x4  __attribute__((ext_vector_type(4)));

static __device__ __forceinline__ unsigned short f2bf(float f) {
    unsigned int u = __float_as_uint(f);
    u += 0x7FFFu + ((u >> 16) & 1u);   // RNE
    return (unsigned short)(u >> 16);
}
static __device__ __forceinline__ float bf2f(unsigned short h) {
    return __uint_as_float(((unsigned int)h) << 16);
}
static __device__ __forceinline__ unsigned int pkbf(float a, float b) {
    unsigned int ua = __float_as_uint(a), ub = __float_as_uint(b);
    ua += 0x7FFFu + ((ua >> 16) & 1u);
    ub += 0x7FFFu + ((ub >> 16) & 1u);
    return (ua >> 16) | (ub & 0xFFFF0000u);
}
static __device__ __forceinline__ float silu(float x) {
    return x / (1.0f + __expf(-x));
}
// cardinal cubic B-spline (fallback path)
static __device__ __forceinline__ float n3(float t) {
    float d2 = t - 2.0f;
    float a  = fabsf(d2);
    float p1 = fmaf(fmaf(0.5f, a, -1.0f), d2 * d2, 0.66666667f);
    float dd = fmaxf(2.0f - a, 0.0f);
    float p2 = dd * dd * (dd * (1.0f / 6.0f));
    return a < 1.0f ? p1 : p2;
}

static __device__ __forceinline__ void glds16(const unsigned short* g, unsigned short* l) {
    __builtin_amdgcn_global_load_lds(
        (const __attribute__((address_space(1))) void*)g,
        (__attribute__((address_space(3))) void*)l, 16, 0, 0);
}

// =====================================================================
// W prep: chunk-major [96][256 o][32 k], granule-permuted for LDS banks.
// chunk ch = i>>2 covers x-cols i = ch*4..+3; granule (16B = 8 slots of
// one (o,i)) at index p = o*4 + (((o>>1) + (i&3)) & 3)
// =====================================================================
__global__ void prep_w2(const float* __restrict__ base_w,
                        const float* __restrict__ spline_w,
                        const float* __restrict__ spline_s,
                        unsigned short* __restrict__ Wsw)
{
    int o = blockIdx.x;          // 0..255
    int i = threadIdx.x;         // 0..383
    int bi = o * IN_DIM + i;
    float sc = spline_s[bi];
    const float* sw = spline_w + (size_t)bi * NCOEF;
    uint4 v;
    v.x = pkbf(base_w[bi], sw[0] * sc);
    v.y = pkbf(sw[1] * sc, sw[2] * sc);
    v.z = pkbf(sw[3] * sc, sw[4] * sc);
    v.w = pkbf(sw[5] * sc, sw[6] * sc);
    int ch = i >> 2, g8 = i & 3;
    int p  = o * 4 + (((o >> 1) + g8) & 3);
    *(uint4*)(Wsw + (size_t)ch * (OUT_DIM * BK2) + p * 8) = v;
}

// =====================================================================
// prep_ctxw: ctx_w [128 n][256 k] f32 -> bf16 row-major (L2-resident B
// operand, read directly by ctx_gemm fragments — no per-block staging)
// =====================================================================
__global__ void prep_ctxw(const float* __restrict__ ctx_w,
                          unsigned short* __restrict__ B)
{
    int n  = blockIdx.x;         // 0..127
    int k4 = threadIdx.x;        // 0..63
    float4 v = *(const float4*)(ctx_w + (size_t)n * CTX_DIM + k4 * 4);
    *(uint2*)&B[(size_t)n * CTX_DIM + k4 * 4] =
        make_uint2(pkbf(v.x, v.y), pkbf(v.z, v.w));
}

// =====================================================================
// gather_x: pure grid-stride gather, no LDS, no barriers.
// Xbf[e][0:256] = bf16(node_emb[pair[e][0]]) | bf16(node_emb[pair[e][1]])
// wave = 2 row-halves: 32 lanes x float4 = 512B coalesced read,
// 32 lanes x 8B = 256B coalesced write.
// =====================================================================
__global__ __launch_bounds__(256)
void gather_x(const float* __restrict__ node_emb,
              const int*   __restrict__ pair,
              unsigned short* __restrict__ Xbf)
{
    const int stride = gridDim.x * blockDim.x;
    const int total  = NEDGES * 64;          // (e, which, f4) tasks
    for (int id = blockIdx.x * blockDim.x + threadIdx.x; id < total; id += stride) {
        int f4    = id & 31;
        int which = (id >> 5) & 1;
        int e     = id >> 6;
        int node  = pair[e * 2 + which];
        float4 v = *(const float4*)(node_emb + (size_t)node * NODE_DIM + f4 * 4);
        *(uint2*)&Xbf[(size_t)e * IN_DIM + which * NODE_DIM + f4 * 4] =
            make_uint2(pkbf(v.x, v.y), pkbf(v.z, v.w));
    }
}

// =====================================================================
// ctx_gemm: Xbf[e][256:384] = bf16(ctx_emb[e] @ ctx_w^T + ctx_b)
// M=100000 (128/block), N=128, K=256. A dbuf in LDS (1 barrier/kc),
// B fragments read straight from prepped bf16 global (L2).
// =====================================================================
#define CG_STR 72
#define CG_ESTR 136
__global__ __launch_bounds__(512, 4)
void ctx_gemm(const float* __restrict__ ctx_emb,
              const unsigned short* __restrict__ ctxwB,
              const float* __restrict__ ctx_b,
              unsigned short* __restrict__ Xbf)
{
    __shared__ unsigned short sm[2 * 128 * CG_STR];   // 36864 B
    const int tid    = threadIdx.x;
    const int e_base = blockIdx.x * 128;
    const int wid    = tid >> 6;
    const int lan    = tid & 63;
    const int lrow   = lan & 15;
    const int lquad  = lan >> 4;
    const int m0     = (wid & 1) * 64;
    const int n0     = (wid >> 1) * 32;

    f32x4 acc[4][2];
    #pragma unroll
    for (int a = 0; a < 4; ++a)
        #pragma unroll
        for (int b = 0; b < 2; ++b) { f32x4 z = {0.f,0.f,0.f,0.f}; acc[a][b] = z; }

    // stage kc=0 into buf0
    #pragma unroll
    for (int it = 0; it < 4; ++it) {
        int id = it * 512 + tid;
        int r  = id >> 4;
        int c4 = id & 15;
        int eg = e_base + r; if (eg >= NEDGES) eg = NEDGES - 1;
        float4 v = *(const float4*)(ctx_emb + (size_t)eg * CTX_DIM + c4 * 4);
        *(uint2*)&sm[r * CG_STR + c4 * 4] = make_uint2(pkbf(v.x, v.y), pkbf(v.z, v.w));
    }
    __syncthreads();

    for (int kc = 0; kc < 4; ++kc) {
        if (kc + 1 < 4) {
            unsigned short* nb = sm + ((kc + 1) & 1) * 128 * CG_STR;
            #pragma unroll
            for (int it = 0; it < 4; ++it) {
                int id = it * 512 + tid;
                int r  = id >> 4;
                int c4 = id & 15;
                int eg = e_base + r; if (eg >= NEDGES) eg = NEDGES - 1;
                float4 v = *(const float4*)(ctx_emb + (size_t)eg * CTX_DIM + (kc + 1) * 64 + c4 * 4);
                *(uint2*)&nb[r * CG_STR + c4 * 4] = make_uint2(pkbf(v.x, v.y), pkbf(v.z, v.w));
            }
        }
        const unsigned short* sa = sm + (kc & 1) * 128 * CG_STR;
        #pragma unroll
        for (int ks = 0; ks < 2; ++ks) {
            int koff = ks * 32 + lquad * 8;
            bf16x8 af[4], bfr[2];
            #pragma unroll
            for (int mt = 0; mt < 4; ++mt)
                af[mt] = *(const bf16x8*)&sa[(m0 + mt*16 + lrow) * CG_STR + koff];
            #pragma unroll
            for (int nt = 0; nt < 2; ++nt)
                bfr[nt] = *(const bf16x8*)&ctxwB[(size_t)(n0 + nt*16 + lrow) * CTX_DIM + kc * 64 + koff];
            #pragma unroll
            for (int mt = 0; mt < 4; ++mt)
                #pragma unroll
                for (int nt = 0; nt < 2; ++nt)
                    acc[mt][nt] = __builtin_amdgcn_mfma_f32_16x16x32_bf16(
                        af[mt], bfr[nt], acc[mt][nt], 0, 0, 0);
        }
        __syncthreads();
    }

    // epilogue: +bias, stage to LDS, coalesced 8B global writes
    #pragma unroll
    for (int nt = 0; nt < 2; ++nt) {
        int col = n0 + nt * 16 + lrow;
        float cb = ctx_b[col];
        #pragma unroll
        for (int mt = 0; mt < 4; ++mt)
            #pragma unroll
            for (int r = 0; r < 4; ++r) {
                int row = m0 + mt * 16 + lquad * 4 + r;
                sm[row * CG_ESTR + col] = f2bf(acc[mt][nt][r] + cb);
            }
    }
    __syncthreads();
    #pragma unroll
    for (int it = 0; it < 8; ++it) {
        int id  = it * 512 + tid;       // 128 rows x 32 uint2-groups
        int row = id >> 5;
        int g   = id & 31;
        int eg  = e_base + row; if (eg >= NEDGES) eg = NEDGES - 1;
        *(uint2*)&Xbf[(size_t)eg * IN_DIM + 256 + g * 4] = *(uint2*)&sm[row * CG_ESTR + g * 4];
    }
}

// =====================================================================
// kan_gemm2: out = A(x) @ W^T with K-reordered A generated in-flight.
// dbuf A + dbuf B, one barrier per BK=32 chunk.  (UNCHANGED this round)
// =====================================================================
#define A2STR  40                          // 32 + 8 pad (ushorts)
#define A2SZ   (BM2 * A2STR)               // 5120
#define B2SZ   (OUT_DIM * BK2)             // 8192
#define OFF_A0 0
#define OFF_A1 A2SZ
#define OFF_B0 (2 * A2SZ)
#define OFF_B1 (2 * A2SZ + B2SZ)
#define LDS2   (2 * A2SZ + 2 * B2SZ)       // 26624 ush = 53248 B

// one x element -> 8 bf16 slots [silu | c0..c6], single b128 LDS write.
// spline: u=frac(t); 4 nonzero pieces Q0..Q3 positioned by 128-bit shift.
static __device__ __forceinline__ void gen_elem(
    unsigned short xh, float hinv, float b0, unsigned short* dst)
{
    float x  = bf2f(xh);
    float sl = silu(x);
    unsigned short slh = f2bf(sl);
    float t  = fmaf(x, hinv, b0);
    float jf = floorf(t);
    int   j0 = (int)jf;
    float u  = t - jf;
    float u2 = u * u, u3 = u2 * u;
    float Q0 = u3 * 0.16666667f;
    float d  = 1.0f - u;
    float Q3 = d * d * d * 0.16666667f;
    float Q1 = fmaf(0.5f, u + u2 - u3, 0.16666667f);
    float Q2 = fmaf(0.5f, u3, 0.66666667f - u2);
    // payload slots ascending: [Q3 @ g=j0-2, Q2, Q1, Q0 @ g=j0+1]
    unsigned plo = pkbf(Q3, Q2);
    unsigned phi = pkbf(Q1, Q0);
    unsigned long long P = ((unsigned long long)phi << 32) | plo;
    int sh = (j0 << 4) - 32;
    unsigned a  = (unsigned)sh;
    unsigned na = 0u - a;
    unsigned long long lo =
        (a  < 64u) ? (P << (a  & 63u)) : ((na < 64u) ? (P >> (na & 63u)) : 0ull);
    unsigned b2 = a - 64u;
    unsigned nb = 0u - b2;
    unsigned long long hi =
        (b2 < 64u) ? (P << (b2 & 63u)) : ((nb < 64u) ? (P >> (nb & 63u)) : 0ull);
    lo = (lo & ~0xFFFFull) | (unsigned long long)slh;   // slot0 = silu
    uint4 w;
    w.x = (unsigned)lo; w.y = (unsigned)(lo >> 32);
    w.z = (unsigned)hi; w.w = (unsigned)(hi >> 32);
    *(uint4*)dst = w;
}

__global__ __launch_bounds__(THR2, 4)
void kan_gemm2(const unsigned short* __restrict__ Wsw,
               const unsigned short* __restrict__ Xbf,
               const float* __restrict__ grid,
               float* __restrict__ out)
{
    __shared__ unsigned short smem[LDS2];
    const int tid    = threadIdx.x;
    const int e_base = blockIdx.x * BM2;
    const int wid    = tid >> 6;
    const int lan    = tid & 63;
    const int lrow   = lan & 15;
    const int lquad  = lan >> 4;
    const int m0     = (wid & 1) * 64;
    const int n0     = (wid >> 1) * 64;

    const float g0   = grid[0];
    const float hinv = 1.0f / (grid[1] - grid[0]);
    const float b0   = -g0 * hinv;

    // gen assignment: one elem/thread/chunk
    const int grow = tid >> 2;           // 0..127
    const int gcol = tid & 3;
    int geg = e_base + grow; if (geg >= NEDGES) geg = NEDGES - 1;
    const unsigned short* xp = Xbf + (size_t)geg * IN_DIM + gcol;
    const unsigned awr = grow * A2STR + gcol * 8;

    f32x4 acc[4][4];
    #pragma unroll
    for (int a = 0; a < 4; ++a)
        #pragma unroll
        for (int b = 0; b < 4; ++b) { f32x4 z = {0.f,0.f,0.f,0.f}; acc[a][b] = z; }

    unsigned short xc = xp[0];
    unsigned short xn = xp[4];

    // prologue: B(0) DMA + A(0) gen
    #pragma unroll
    for (int it = 0; it < 2; ++it) {
        int id = it * THR2 + tid;
        glds16(Wsw + id * 8, &smem[OFF_B0 + id * 8]);
    }
    gen_elem(xc, hinv, b0, &smem[OFF_A0 + awr]);
    __syncthreads();

    for (int kb = 0; kb < NCH2; ++kb) {
        const int cur = kb & 1;
        if (kb + 1 < NCH2) {
            const unsigned short* wc = Wsw + (size_t)(kb + 1) * B2SZ;
            unsigned boff = cur ? OFF_B0 : OFF_B1;   // next buffer
            #pragma unroll
            for (int it = 0; it < 2; ++it) {
                int id = it * THR2 + tid;
                glds16(wc + id * 8, &smem[boff + id * 8]);
            }
            unsigned short xh = xn;
            if (kb + 2 < NCH2) xn = xp[(kb + 2) * 4];
            gen_elem(xh, hinv, b0, &smem[(cur ? OFF_A0 : OFF_A1) + awr]);
        }
        // MFMA on current buffers
        const unsigned ab = cur ? OFF_A1 : OFF_A0;
        const unsigned bb = cur ? OFF_B1 : OFF_B0;
        bf16x8 af[4], bfr[4];
        #pragma unroll
        for (int mt = 0; mt < 4; ++mt)
            af[mt] = *(const bf16x8*)&smem[ab + (m0 + mt*16 + lrow) * A2STR + lquad * 8];
        #pragma unroll
        for (int nt = 0; nt < 4; ++nt) {
            int n = n0 + nt * 16 + lrow;
            bfr[nt] = *(const bf16x8*)&smem[bb + n * 32 + ((((n >> 1) + lquad) & 3) << 3)];
        }
        #pragma unroll
        for (int mt = 0; mt < 4; ++mt)
            #pragma unroll
            for (int nt = 0; nt < 4; ++nt)
                acc[mt][nt] = __builtin_amdgcn_mfma_f32_16x16x32_bf16(
                    af[mt], bfr[nt], acc[mt][nt], 0, 0, 0);
        __syncthreads();
    }

    // epilogue: C row = edge (m), col = out (n)
    #pragma unroll
    for (int mt = 0; mt < 4; ++mt) {
        #pragma unroll
        for (int r = 0; r < 4; ++r) {
            int row = m0 + mt * 16 + lquad * 4 + r;
            int eg  = e_base + row;
            if (eg < NEDGES) {
                float* op = out + (size_t)eg * OUT_DIM + n0 + lrow;
                #pragma unroll
                for (int nt = 0; nt < 4; ++nt)
                    op[nt * 16] = acc[mt][nt][r];
            }
        }
    }
}

// =====================================================================
// FALLBACK (no workspace): round-1 fused kernel, correctness-only
// =====================================================================
#define XSTR 392
#define FSTR 72
#define FOFF_X 0
#define FOFF_A (128 * XSTR)
#define FOFF_B (FOFF_A + 128 * FSTR)
#define FLDS (FOFF_B + OUT_DIM * FSTR)

__global__ __launch_bounds__(512, 2)
void fused_fallback(const float* __restrict__ node_emb,
                    const float* __restrict__ ctx_emb,
                    const int*   __restrict__ pair,
                    const float* __restrict__ ctx_w,
                    const float* __restrict__ ctx_b,
                    const float* __restrict__ base_w,
                    const float* __restrict__ spline_w,
                    const float* __restrict__ spline_s,
                    const float* __restrict__ grid,
                    float* __restrict__ out)
{
    __shared__ unsigned short smem[FLDS];
    const int tid    = threadIdx.x;
    const int e_base = blockIdx.x * 128;
    const int wid    = tid >> 6;
    const int lan    = tid & 63;
    const int lrow   = lan & 15;
    const int lquad  = lan >> 4;

    #pragma unroll
    for (int it = 0; it < 16; ++it) {
        int id    = it * 512 + tid;
        int lane4 = id & 31;
        int e     = (id >> 5) & 127;
        int which = id >> 12;
        int eg = e_base + e; if (eg >= NEDGES) eg = NEDGES - 1;
        int node = pair[eg * 2 + which];
        const float4 v = *(const float4*)(node_emb + (size_t)node * NODE_DIM + lane4 * 4);
        *(ushort4*)&smem[FOFF_X + e * XSTR + which * NODE_DIM + lane4 * 4] =
            make_ushort4(f2bf(v.x), f2bf(v.y), f2bf(v.z), f2bf(v.w));
    }
    {
        f32x4 cacc[4][2];
        #pragma unroll
        for (int a = 0; a < 4; ++a)
            #pragma unroll
            for (int b = 0; b < 2; ++b) { f32x4 z = {0.f,0.f,0.f,0.f}; cacc[a][b] = z; }
        const int m0 = (wid & 1) * 64;
        const int n0 = (wid >> 1) * 32;
        for (int kc = 0; kc < 4; ++kc) {
            #pragma unroll
            for (int it = 0; it < 4; ++it) {
                int id = it * 512 + tid;
                int r  = id >> 4;
                int c4 = id & 15;
                int eg = e_base + r; if (eg >= NEDGES) eg = NEDGES - 1;
                float4 v = *(const float4*)(ctx_emb + (size_t)eg * CTX_DIM + kc * 64 + c4 * 4);
                *(ushort4*)&smem[FOFF_A + r * FSTR + c4 * 4] =
                    make_ushort4(f2bf(v.x), f2bf(v.y), f2bf(v.z), f2bf(v.w));
                float4 w = *(const float4*)(ctx_w + (size_t)r * CTX_DIM + kc * 64 + c4 * 4);
                *(ushort4*)&smem[FOFF_B + r * FSTR + c4 * 4] =
                    make_ushort4(f2bf(w.x), f2bf(w.y), f2bf(w.z), f2bf(w.w));
            }
            __syncthreads();
            #pragma unroll
            for (int ks = 0; ks < 2; ++ks) {
                int koff = ks * 32 + lquad * 8;
                bf16x8 af[4], bfr[2];
                #pragma unroll
                for (int mt = 0; mt < 4; ++mt)
                    af[mt] = *(const bf16x8*)&smem[FOFF_A + (m0 + mt*16 + lrow) * FSTR + koff];
                #pragma unroll
                for (int nt = 0; nt < 2; ++nt)
                    bfr[nt] = *(const bf16x8*)&smem[FOFF_B + (n0 + nt*16 + lrow) * FSTR + koff];
                #pragma unroll
                for (int mt = 0; mt < 4; ++mt)
                    #pragma unroll
                    for (int nt = 0; nt < 2; ++nt)
                        cacc[mt][nt] = __builtin_amdgcn_mfma_f32_16x16x32_bf16(
                            af[mt], bfr[nt], cacc[mt][nt], 0, 0, 0);
            }
            __syncthreads();
        }
        #pragma unroll
        for (int mt = 0; mt < 4; ++mt)
            #pragma unroll
            for (int nt = 0; nt < 2; ++nt)
                #pragma unroll
                for (int r = 0; r < 4; ++r) {
                    int row = m0 + mt*16 + lquad*4 + r;
                    int col = n0 + nt*16 + lrow;
                    smem[FOFF_X + row * XSTR + 256 + col] = f2bf(cacc[mt][nt][r] + ctx_b[col]);
                }
    }
    __syncthreads();

    const float g0   = grid[0];
    const float hinv = 1.0f / (grid[1] - grid[0]);

    f32x4 acc[4][4];
    #pragma unroll
    for (int a = 0; a < 4; ++a)
        #pragma unroll
        for (int b = 0; b < 4; ++b) { f32x4 z = {0.f,0.f,0.f,0.f}; acc[a][b] = z; }

    const int m0 = (wid & 1) * 64;
    const int n0 = (wid >> 1) * 64;

    for (int kb = 0; kb < 48; ++kb) {
        const int seg = kb / 6;
        const int i0  = (kb - seg * 6) * 64;
        #pragma unroll
        for (int it = 0; it < 4; ++it) {
            int id = it * 512 + tid;
            int e  = id >> 4;
            int qq = id & 15;
            ushort4 xv = *(const ushort4*)&smem[FOFF_X + e * XSTR + i0 + qq * 4];
            float x0 = bf2f(xv.x), x1 = bf2f(xv.y), x2 = bf2f(xv.z), x3 = bf2f(xv.w);
            unsigned short r0, r1, r2, r3;
            if (seg == 0) {
                r0 = f2bf(silu(x0)); r1 = f2bf(silu(x1));
                r2 = f2bf(silu(x2)); r3 = f2bf(silu(x3));
            } else {
                const float cf = (float)(seg - 1);
                r0 = f2bf(n3((x0 - g0) * hinv - cf));
                r1 = f2bf(n3((x1 - g0) * hinv - cf));
                r2 = f2bf(n3((x2 - g0) * hinv - cf));
                r3 = f2bf(n3((x3 - g0) * hinv - cf));
            }
            *(ushort4*)&smem[FOFF_A + e * FSTR + qq * 4] = make_ushort4(r0, r1, r2, r3);
        }
        #pragma unroll
        for (int it = 0; it < 4; ++it) {
            int id = it * 512 + tid;
            int o  = id >> 4;
            int qq = id & 15;
            unsigned short r0, r1, r2, r3;
            if (seg == 0) {
                const float4 w = *(const float4*)(base_w + (size_t)o * IN_DIM + i0 + qq * 4);
                r0 = f2bf(w.x); r1 = f2bf(w.y); r2 = f2bf(w.z); r3 = f2bf(w.w);
            } else {
                int c  = seg - 1;
                int bi = o * IN_DIM + i0 + qq * 4;
                r0 = f2bf(spline_w[(size_t)(bi    ) * NCOEF + c] * spline_s[bi    ]);
                r1 = f2bf(spline_w[(size_t)(bi + 1) * NCOEF + c] * spline_s[bi + 1]);
                r2 = f2bf(spline_w[(size_t)(bi + 2) * NCOEF + c] * spline_s[bi + 2]);
                r3 = f2bf(spline_w[(size_t)(bi + 3) * NCOEF + c] * spline_s[bi + 3]);
            }
            *(ushort4*)&smem[FOFF_B + o * FSTR + qq * 4] = make_ushort4(r0, r1, r2, r3);
        }
        __syncthreads();
        #pragma unroll
        for (int ks = 0; ks < 2; ++ks) {
            int koff = ks * 32 + lquad * 8;
            bf16x8 af[4], bfr[4];
            #pragma unroll
            for (int mt = 0; mt < 4; ++mt)
                af[mt] = *(const bf16x8*)&smem[FOFF_A + (m0 + mt*16 + lrow) * FSTR + koff];
            #pragma unroll
            for (int nt = 0; nt < 4; ++nt)
                bfr[nt] = *(const bf16x8*)&smem[FOFF_B + (n0 + nt*16 + lrow) * FSTR + koff];
            #pragma unroll
            for (int mt = 0; mt < 4; ++mt)
                #pragma unroll
                for (int nt = 0; nt < 4; ++nt)
                    acc[mt][nt] = __builtin_amdgcn_mfma_f32_16x16x32_bf16(
                        af[mt], bfr[nt], acc[mt][nt], 0, 0, 0);
        }
        __syncthreads();
    }

    #pragma unroll
    for (int mt = 0; mt < 4; ++mt) {
        #pragma unroll
        for (int r = 0; r < 4; ++r) {
            int row = m0 + mt*16 + lquad*4 + r;
            int eg  = e_base + row;
            if (eg < NEDGES) {
                float* op = out + (size_t)eg * OUT_DIM + n0 + lrow;
                #pragma unroll
                for (int nt = 0; nt < 4; ++nt)
                    op[nt * 16] = acc[mt][nt][r];
            }
        }
    }
}

// ---------------- launch ----------------
extern "C" void kernel_launch(void* const* d_in, const int* in_sizes, int n_in,
                              void* d_out, int out_size, void* d_ws, size_t ws_size,
                              hipStream_t stream)
{
    const float* node_emb = (const float*)d_in[0];
    const float* ctx_emb  = (const float*)d_in[1];
    const int*   pair     = (const int*)d_in[2];
    const float* ctx_w    = (const float*)d_in[3];
    const float* ctx_b    = (const float*)d_in[4];
    const float* base_w   = (const float*)d_in[5];
    const float* spline_w = (const float*)d_in[6];
    const float* spline_s = (const float*)d_in[7];
    const float* grid     = (const float*)d_in[8];
    float* out = (float*)d_out;

    const int nblk = (NEDGES + BM2 - 1) / BM2;     // 782
    const size_t xoff    = 2u * 1024u * 1024u;
    const size_t ctxwoff = 1572864u;               // after Wsw (96*256*32*2 B)
    const size_t need = xoff + (size_t)NEDGES * IN_DIM * sizeof(unsigned short);

    if (ws_size >= need) {
        unsigned short* Wsw   = (unsigned short*)d_ws;
        unsigned short* CtxwB = (unsigned short*)((char*)d_ws + ctxwoff);
        unsigned short* Xbf   = (unsigned short*)((char*)d_ws + xoff);
        prep_w2<<<OUT_DIM, IN_DIM, 0, stream>>>(base_w, spline_w, spline_s, Wsw);
        prep_ctxw<<<128, 64, 0, stream>>>(ctx_w, CtxwB);
        gather_x<<<2048, 256, 0, stream>>>(node_emb, pair, Xbf);
        ctx_gemm<<<nblk, 512, 0, stream>>>(ctx_emb, CtxwB, ctx_b, Xbf);
        kan_gemm2<<<nblk, THR2, 0, stream>>>(Wsw, Xbf, grid, out);
    } else {
        fused_fallback<<<nblk, 512, 0, stream>>>(
            node_emb, ctx_emb, pair, ctx_w, ctx_b, base_w, spline_w, spline_s, grid, out);
    }
}

// Round 2
// 446.142 us; speedup vs baseline: 1.0157x; 1.0157x over previous
//
#include <hip/hip_runtime.h>

// ---------------- problem constants ----------------
#define NEDGES   100000
#define NODE_DIM 128
#define CTX_DIM  256
#define OUT_DIM  256
#define IN_DIM   384
#define NCOEF    7

// kan_gemm2 tiling: K' = i*8 + slot, slot0=silu, slot1..7=spline c=slot-1
#define BM2      128
#define BK2      32            // 4 x-cols * 8 slots
#define NCH2     96            // IN_DIM / 4
#define THR2     512           // 8 waves

typedef __bf16 bf16x8 __attribute__((ext_vector_type(8)));
typedef float  f32x4  __attribute__((ext_vector_type(4)));

static __device__ __forceinline__ unsigned short f2bf(float f) {
    unsigned int u = __float_as_uint(f);
    u += 0x7FFFu + ((u >> 16) & 1u);   // RNE
    return (unsigned short)(u >> 16);
}
static __device__ __forceinline__ float bf2f(unsigned short h) {
    return __uint_as_float(((unsigned int)h) << 16);
}
static __device__ __forceinline__ unsigned int pkbf(float a, float b) {
    unsigned int ua = __float_as_uint(a), ub = __float_as_uint(b);
    ua += 0x7FFFu + ((ua >> 16) & 1u);
    ub += 0x7FFFu + ((ub >> 16) & 1u);
    return (ua >> 16) | (ub & 0xFFFF0000u);
}
static __device__ __forceinline__ float silu(float x) {
    return x / (1.0f + __expf(-x));
}
// cardinal cubic B-spline (fallback path)
static __device__ __forceinline__ float n3(float t) {
    float d2 = t - 2.0f;
    float a  = fabsf(d2);
    float p1 = fmaf(fmaf(0.5f, a, -1.0f), d2 * d2, 0.66666667f);
    float dd = fmaxf(2.0f - a, 0.0f);
    float p2 = dd * dd * (dd * (1.0f / 6.0f));
    return a < 1.0f ? p1 : p2;
}

static __device__ __forceinline__ void glds16(const unsigned short* g, unsigned short* l) {
    __builtin_amdgcn_global_load_lds(
        (const __attribute__((address_space(1))) void*)g,
        (__attribute__((address_space(3))) void*)l, 16, 0, 0);
}

// =====================================================================
// W prep: chunk-major [96][256 o][32 k], granule-permuted for LDS banks.
// chunk ch = i>>2 covers x-cols i = ch*4..+3; granule (16B = 8 slots of
// one (o,i)) at index p = o*4 + (((o>>1) + (i&3)) & 3)
// =====================================================================
__global__ void prep_w2(const float* __restrict__ base_w,
                        const float* __restrict__ spline_w,
                        const float* __restrict__ spline_s,
                        unsigned short* __restrict__ Wsw)
{
    int o = blockIdx.x;          // 0..255
    int i = threadIdx.x;         // 0..383
    int bi = o * IN_DIM + i;
    float sc = spline_s[bi];
    const float* sw = spline_w + (size_t)bi * NCOEF;
    uint4 v;
    v.x = pkbf(base_w[bi], sw[0] * sc);
    v.y = pkbf(sw[1] * sc, sw[2] * sc);
    v.z = pkbf(sw[3] * sc, sw[4] * sc);
    v.w = pkbf(sw[5] * sc, sw[6] * sc);
    int ch = i >> 2, g8 = i & 3;
    int p  = o * 4 + (((o >> 1) + g8) & 3);
    *(uint4*)(Wsw + (size_t)ch * (OUT_DIM * BK2) + p * 8) = v;
}

// =====================================================================
// prep_ctxw: ctx_w [128 n][256 k] f32 -> bf16 row-major (L2-resident B
// operand, read directly by ctx_gemm fragments — no per-block staging)
// =====================================================================
__global__ void prep_ctxw(const float* __restrict__ ctx_w,
                          unsigned short* __restrict__ B)
{
    int n  = blockIdx.x;         // 0..127
    int k4 = threadIdx.x;        // 0..63
    float4 v = *(const float4*)(ctx_w + (size_t)n * CTX_DIM + k4 * 4);
    *(uint2*)&B[(size_t)n * CTX_DIM + k4 * 4] =
        make_uint2(pkbf(v.x, v.y), pkbf(v.z, v.w));
}

// =====================================================================
// ctx_gemm: CtxB[e][0:128] = bf16(ctx_emb[e] @ ctx_w^T + ctx_b)
// M=100000 (128/block), N=128, K=256. A dbuf in LDS (1 barrier/kc),
// B fragments read straight from prepped bf16 global (L2).
// =====================================================================
#define CG_STR 72
#define CG_ESTR 136
__global__ __launch_bounds__(512, 4)
void ctx_gemm(const float* __restrict__ ctx_emb,
              const unsigned short* __restrict__ ctxwB,
              const float* __restrict__ ctx_b,
              unsigned short* __restrict__ CtxB)
{
    __shared__ unsigned short sm[2 * 128 * CG_STR];   // 36864 B
    const int tid    = threadIdx.x;
    const int e_base = blockIdx.x * 128;
    const int wid    = tid >> 6;
    const int lan    = tid & 63;
    const int lrow   = lan & 15;
    const int lquad  = lan >> 4;
    const int m0     = (wid & 1) * 64;
    const int n0     = (wid >> 1) * 32;

    f32x4 acc[4][2];
    #pragma unroll
    for (int a = 0; a < 4; ++a)
        #pragma unroll
        for (int b = 0; b < 2; ++b) { f32x4 z = {0.f,0.f,0.f,0.f}; acc[a][b] = z; }

    // stage kc=0 into buf0
    #pragma unroll
    for (int it = 0; it < 4; ++it) {
        int id = it * 512 + tid;
        int r  = id >> 4;
        int c4 = id & 15;
        int eg = e_base + r; if (eg >= NEDGES) eg = NEDGES - 1;
        float4 v = *(const float4*)(ctx_emb + (size_t)eg * CTX_DIM + c4 * 4);
        *(uint2*)&sm[r * CG_STR + c4 * 4] = make_uint2(pkbf(v.x, v.y), pkbf(v.z, v.w));
    }
    __syncthreads();

    for (int kc = 0; kc < 4; ++kc) {
        if (kc + 1 < 4) {
            unsigned short* nb = sm + ((kc + 1) & 1) * 128 * CG_STR;
            #pragma unroll
            for (int it = 0; it < 4; ++it) {
                int id = it * 512 + tid;
                int r  = id >> 4;
                int c4 = id & 15;
                int eg = e_base + r; if (eg >= NEDGES) eg = NEDGES - 1;
                float4 v = *(const float4*)(ctx_emb + (size_t)eg * CTX_DIM + (kc + 1) * 64 + c4 * 4);
                *(uint2*)&nb[r * CG_STR + c4 * 4] = make_uint2(pkbf(v.x, v.y), pkbf(v.z, v.w));
            }
        }
        const unsigned short* sa = sm + (kc & 1) * 128 * CG_STR;
        #pragma unroll
        for (int ks = 0; ks < 2; ++ks) {
            int koff = ks * 32 + lquad * 8;
            bf16x8 af[4], bfr[2];
            #pragma unroll
            for (int mt = 0; mt < 4; ++mt)
                af[mt] = *(const bf16x8*)&sa[(m0 + mt*16 + lrow) * CG_STR + koff];
            #pragma unroll
            for (int nt = 0; nt < 2; ++nt)
                bfr[nt] = *(const bf16x8*)&ctxwB[(size_t)(n0 + nt*16 + lrow) * CTX_DIM + kc * 64 + koff];
            #pragma unroll
            for (int mt = 0; mt < 4; ++mt)
                #pragma unroll
                for (int nt = 0; nt < 2; ++nt)
                    acc[mt][nt] = __builtin_amdgcn_mfma_f32_16x16x32_bf16(
                        af[mt], bfr[nt], acc[mt][nt], 0, 0, 0);
        }
        __syncthreads();
    }

    // epilogue: +bias, stage to LDS, coalesced 8B global writes
    #pragma unroll
    for (int nt = 0; nt < 2; ++nt) {
        int col = n0 + nt * 16 + lrow;
        float cb = ctx_b[col];
        #pragma unroll
        for (int mt = 0; mt < 4; ++mt)
            #pragma unroll
            for (int r = 0; r < 4; ++r) {
                int row = m0 + mt * 16 + lquad * 4 + r;
                sm[row * CG_ESTR + col] = f2bf(acc[mt][nt][r] + cb);
            }
    }
    __syncthreads();
    #pragma unroll
    for (int it = 0; it < 8; ++it) {
        int id  = it * 512 + tid;       // 128 rows x 32 uint2-groups
        int row = id >> 5;
        int g   = id & 31;
        int eg  = e_base + row; if (eg >= NEDGES) eg = NEDGES - 1;
        *(uint2*)&CtxB[(size_t)eg * 128 + g * 4] = *(uint2*)&sm[row * CG_ESTR + g * 4];
    }
}

// =====================================================================
// kan_gemm2: out = A(x) @ W^T with K-reordered A generated in-flight.
// x sourced directly: subj/obj from node_emb (f32 gather, hidden by the
// 2-chunk prefetch distance), ctx from CtxB (bf16). No Xbf staging.
// dbuf A + dbuf B, one barrier per BK=32 chunk.
// =====================================================================
#define A2STR  40                          // 32 + 8 pad (ushorts)
#define A2SZ   (BM2 * A2STR)               // 5120
#define B2SZ   (OUT_DIM * BK2)             // 8192
#define OFF_A0 0
#define OFF_A1 A2SZ
#define OFF_B0 (2 * A2SZ)
#define OFF_B1 (2 * A2SZ + B2SZ)
#define LDS2   (2 * A2SZ + 2 * B2SZ)       // 26624 ush = 53248 B

// one x element -> 8 bf16 slots [silu | c0..c6], single b128 LDS write.
// spline: u=frac(t); 4 nonzero pieces Q0..Q3 positioned by 128-bit shift.
static __device__ __forceinline__ void gen_elem(
    float x, float hinv, float b0, unsigned short* dst)
{
    float sl = silu(x);
    unsigned short slh = f2bf(sl);
    float t  = fmaf(x, hinv, b0);
    float jf = floorf(t);
    int   j0 = (int)jf;
    float u  = t - jf;
    float u2 = u * u, u3 = u2 * u;
    float Q0 = u3 * 0.16666667f;
    float d  = 1.0f - u;
    float Q3 = d * d * d * 0.16666667f;
    float Q1 = fmaf(0.5f, u + u2 - u3, 0.16666667f);
    float Q2 = fmaf(0.5f, u3, 0.66666667f - u2);
    // payload slots ascending: [Q3 @ g=j0-2, Q2, Q1, Q0 @ g=j0+1]
    unsigned plo = pkbf(Q3, Q2);
    unsigned phi = pkbf(Q1, Q0);
    unsigned long long P = ((unsigned long long)phi << 32) | plo;
    int sh = (j0 << 4) - 32;
    unsigned a  = (unsigned)sh;
    unsigned na = 0u - a;
    unsigned long long lo =
        (a  < 64u) ? (P << (a  & 63u)) : ((na < 64u) ? (P >> (na & 63u)) : 0ull);
    unsigned b2 = a - 64u;
    unsigned nb = 0u - b2;
    unsigned long long hi =
        (b2 < 64u) ? (P << (b2 & 63u)) : ((nb < 64u) ? (P >> (nb & 63u)) : 0ull);
    lo = (lo & ~0xFFFFull) | (unsigned long long)slh;   // slot0 = silu
    uint4 w;
    w.x = (unsigned)lo; w.y = (unsigned)(lo >> 32);
    w.z = (unsigned)hi; w.w = (unsigned)(hi >> 32);
    *(uint4*)dst = w;
}

// x fetch for chunk ch (wave-uniform branch: ch is uniform)
static __device__ __forceinline__ float fetchx(
    const float* ps, const float* po, const unsigned short* pc, int ch)
{
    if (ch < 32) return ps[ch << 2];
    if (ch < 64) return po[(ch - 32) << 2];
    return bf2f(pc[(ch - 64) << 2]);
}

__global__ __launch_bounds__(THR2, 4)
void kan_gemm2(const unsigned short* __restrict__ Wsw,
               const unsigned short* __restrict__ CtxB,
               const float* __restrict__ node_emb,
               const int*   __restrict__ pair,
               const float* __restrict__ grid,
               float* __restrict__ out)
{
    __shared__ unsigned short smem[LDS2];
    const int tid    = threadIdx.x;
    const int e_base = blockIdx.x * BM2;
    const int wid    = tid >> 6;
    const int lan    = tid & 63;
    const int lrow   = lan & 15;
    const int lquad  = lan >> 4;
    const int m0     = (wid & 1) * 64;
    const int n0     = (wid >> 1) * 64;

    const float g0   = grid[0];
    const float hinv = 1.0f / (grid[1] - grid[0]);
    const float b0   = -g0 * hinv;

    // gen assignment: one elem/thread/chunk
    const int grow = tid >> 2;           // 0..127
    const int gcol = tid & 3;
    int geg = e_base + grow; if (geg >= NEDGES) geg = NEDGES - 1;
    const int nsub = pair[geg * 2 + 0];
    const int nobj = pair[geg * 2 + 1];
    const float* ps = node_emb + (size_t)nsub * NODE_DIM + gcol;
    const float* po = node_emb + (size_t)nobj * NODE_DIM + gcol;
    const unsigned short* pc = CtxB + (size_t)geg * 128 + gcol;
    const unsigned awr = grow * A2STR + gcol * 8;

    f32x4 acc[4][4];
    #pragma unroll
    for (int a = 0; a < 4; ++a)
        #pragma unroll
        for (int b = 0; b < 4; ++b) { f32x4 z = {0.f,0.f,0.f,0.f}; acc[a][b] = z; }

    float xc = fetchx(ps, po, pc, 0);
    float xn = fetchx(ps, po, pc, 1);

    // prologue: B(0) DMA + A(0) gen
    #pragma unroll
    for (int it = 0; it < 2; ++it) {
        int id = it * THR2 + tid;
        glds16(Wsw + id * 8, &smem[OFF_B0 + id * 8]);
    }
    gen_elem(xc, hinv, b0, &smem[OFF_A0 + awr]);
    __syncthreads();

    for (int kb = 0; kb < NCH2; ++kb) {
        const int cur = kb & 1;
        if (kb + 1 < NCH2) {
            const unsigned short* wc = Wsw + (size_t)(kb + 1) * B2SZ;
            unsigned boff = cur ? OFF_B0 : OFF_B1;   // next buffer
            #pragma unroll
            for (int it = 0; it < 2; ++it) {
                int id = it * THR2 + tid;
                glds16(wc + id * 8, &smem[boff + id * 8]);
            }
            float xh = xn;
            if (kb + 2 < NCH2) xn = fetchx(ps, po, pc, kb + 2);
            gen_elem(xh, hinv, b0, &smem[(cur ? OFF_A0 : OFF_A1) + awr]);
        }
        // MFMA on current buffers
        const unsigned ab = cur ? OFF_A1 : OFF_A0;
        const unsigned bb = cur ? OFF_B1 : OFF_B0;
        bf16x8 af[4], bfr[4];
        #pragma unroll
        for (int mt = 0; mt < 4; ++mt)
            af[mt] = *(const bf16x8*)&smem[ab + (m0 + mt*16 + lrow) * A2STR + lquad * 8];
        #pragma unroll
        for (int nt = 0; nt < 4; ++nt) {
            int n = n0 + nt * 16 + lrow;
            bfr[nt] = *(const bf16x8*)&smem[bb + n * 32 + ((((n >> 1) + lquad) & 3) << 3)];
        }
        #pragma unroll
        for (int mt = 0; mt < 4; ++mt)
            #pragma unroll
            for (int nt = 0; nt < 4; ++nt)
                acc[mt][nt] = __builtin_amdgcn_mfma_f32_16x16x32_bf16(
                    af[mt], bfr[nt], acc[mt][nt], 0, 0, 0);
        __syncthreads();
    }

    // epilogue: C row = edge (m), col = out (n)
    #pragma unroll
    for (int mt = 0; mt < 4; ++mt) {
        #pragma unroll
        for (int r = 0; r < 4; ++r) {
            int row = m0 + mt * 16 + lquad * 4 + r;
            int eg  = e_base + row;
            if (eg < NEDGES) {
                float* op = out + (size_t)eg * OUT_DIM + n0 + lrow;
                #pragma unroll
                for (int nt = 0; nt < 4; ++nt)
                    op[nt * 16] = acc[mt][nt][r];
            }
        }
    }
}

// =====================================================================
// FALLBACK (no workspace): round-1 fused kernel, correctness-only
// =====================================================================
#define XSTR 392
#define FSTR 72
#define FOFF_X 0
#define FOFF_A (128 * XSTR)
#define FOFF_B (FOFF_A + 128 * FSTR)
#define FLDS (FOFF_B + OUT_DIM * FSTR)

__global__ __launch_bounds__(512, 2)
void fused_fallback(const float* __restrict__ node_emb,
                    const float* __restrict__ ctx_emb,
                    const int*   __restrict__ pair,
                    const float* __restrict__ ctx_w,
                    const float* __restrict__ ctx_b,
                    const float* __restrict__ base_w,
                    const float* __restrict__ spline_w,
                    const float* __restrict__ spline_s,
                    const float* __restrict__ grid,
                    float* __restrict__ out)
{
    __shared__ unsigned short smem[FLDS];
    const int tid    = threadIdx.x;
    const int e_base = blockIdx.x * 128;
    const int wid    = tid >> 6;
    const int lan    = tid & 63;
    const int lrow   = lan & 15;
    const int lquad  = lan >> 4;

    #pragma unroll
    for (int it = 0; it < 16; ++it) {
        int id    = it * 512 + tid;
        int lane4 = id & 31;
        int e     = (id >> 5) & 127;
        int which = id >> 12;
        int eg = e_base + e; if (eg >= NEDGES) eg = NEDGES - 1;
        int node = pair[eg * 2 + which];
        const float4 v = *(const float4*)(node_emb + (size_t)node * NODE_DIM + lane4 * 4);
        *(ushort4*)&smem[FOFF_X + e * XSTR + which * NODE_DIM + lane4 * 4] =
            make_ushort4(f2bf(v.x), f2bf(v.y), f2bf(v.z), f2bf(v.w));
    }
    {
        f32x4 cacc[4][2];
        #pragma unroll
        for (int a = 0; a < 4; ++a)
            #pragma unroll
            for (int b = 0; b < 2; ++b) { f32x4 z = {0.f,0.f,0.f,0.f}; cacc[a][b] = z; }
        const int m0 = (wid & 1) * 64;
        const int n0 = (wid >> 1) * 32;
        for (int kc = 0; kc < 4; ++kc) {
            #pragma unroll
            for (int it = 0; it < 4; ++it) {
                int id = it * 512 + tid;
                int r  = id >> 4;
                int c4 = id & 15;
                int eg = e_base + r; if (eg >= NEDGES) eg = NEDGES - 1;
                float4 v = *(const float4*)(ctx_emb + (size_t)eg * CTX_DIM + kc * 64 + c4 * 4);
                *(ushort4*)&smem[FOFF_A + r * FSTR + c4 * 4] =
                    make_ushort4(f2bf(v.x), f2bf(v.y), f2bf(v.z), f2bf(v.w));
                float4 w = *(const float4*)(ctx_w + (size_t)r * CTX_DIM + kc * 64 + c4 * 4);
                *(ushort4*)&smem[FOFF_B + r * FSTR + c4 * 4] =
                    make_ushort4(f2bf(w.x), f2bf(w.y), f2bf(w.z), f2bf(w.w));
            }
            __syncthreads();
            #pragma unroll
            for (int ks = 0; ks < 2; ++ks) {
                int koff = ks * 32 + lquad * 8;
                bf16x8 af[4], bfr[2];
                #pragma unroll
                for (int mt = 0; mt < 4; ++mt)
                    af[mt] = *(const bf16x8*)&smem[FOFF_A + (m0 + mt*16 + lrow) * FSTR + koff];
                #pragma unroll
                for (int nt = 0; nt < 2; ++nt)
                    bfr[nt] = *(const bf16x8*)&smem[FOFF_B + (n0 + nt*16 + lrow) * FSTR + koff];
                #pragma unroll
                for (int mt = 0; mt < 4; ++mt)
                    #pragma unroll
                    for (int nt = 0; nt < 2; ++nt)
                        cacc[mt][nt] = __builtin_amdgcn_mfma_f32_16x16x32_bf16(
                            af[mt], bfr[nt], cacc[mt][nt], 0, 0, 0);
            }
            __syncthreads();
        }
        #pragma unroll
        for (int mt = 0; mt < 4; ++mt)
            #pragma unroll
            for (int nt = 0; nt < 2; ++nt)
                #pragma unroll
                for (int r = 0; r < 4; ++r) {
                    int row = m0 + mt*16 + lquad*4 + r;
                    int col = n0 + nt*16 + lrow;
                    smem[FOFF_X + row * XSTR + 256 + col] = f2bf(cacc[mt][nt][r] + ctx_b[col]);
                }
    }
    __syncthreads();

    const float g0   = grid[0];
    const float hinv = 1.0f / (grid[1] - grid[0]);

    f32x4 acc[4][4];
    #pragma unroll
    for (int a = 0; a < 4; ++a)
        #pragma unroll
        for (int b = 0; b < 4; ++b) { f32x4 z = {0.f,0.f,0.f,0.f}; acc[a][b] = z; }

    const int m0 = (wid & 1) * 64;
    const int n0 = (wid >> 1) * 64;

    for (int kb = 0; kb < 48; ++kb) {
        const int seg = kb / 6;
        const int i0  = (kb - seg * 6) * 64;
        #pragma unroll
        for (int it = 0; it < 4; ++it) {
            int id = it * 512 + tid;
            int e  = id >> 4;
            int qq = id & 15;
            ushort4 xv = *(const ushort4*)&smem[FOFF_X + e * XSTR + i0 + qq * 4];
            float x0 = bf2f(xv.x), x1 = bf2f(xv.y), x2 = bf2f(xv.z), x3 = bf2f(xv.w);
            unsigned short r0, r1, r2, r3;
            if (seg == 0) {
                r0 = f2bf(silu(x0)); r1 = f2bf(silu(x1));
                r2 = f2bf(silu(x2)); r3 = f2bf(silu(x3));
            } else {
                const float cf = (float)(seg - 1);
                r0 = f2bf(n3((x0 - g0) * hinv - cf));
                r1 = f2bf(n3((x1 - g0) * hinv - cf));
                r2 = f2bf(n3((x2 - g0) * hinv - cf));
                r3 = f2bf(n3((x3 - g0) * hinv - cf));
            }
            *(ushort4*)&smem[FOFF_A + e * FSTR + qq * 4] = make_ushort4(r0, r1, r2, r3);
        }
        #pragma unroll
        for (int it = 0; it < 4; ++it) {
            int id = it * 512 + tid;
            int o  = id >> 4;
            int qq = id & 15;
            unsigned short r0, r1, r2, r3;
            if (seg == 0) {
                const float4 w = *(const float4*)(base_w + (size_t)o * IN_DIM + i0 + qq * 4);
                r0 = f2bf(w.x); r1 = f2bf(w.y); r2 = f2bf(w.z); r3 = f2bf(w.w);
            } else {
                int c  = seg - 1;
                int bi = o * IN_DIM + i0 + qq * 4;
                r0 = f2bf(spline_w[(size_t)(bi    ) * NCOEF + c] * spline_s[bi    ]);
                r1 = f2bf(spline_w[(size_t)(bi + 1) * NCOEF + c] * spline_s[bi + 1]);
                r2 = f2bf(spline_w[(size_t)(bi + 2) * NCOEF + c] * spline_s[bi + 2]);
                r3 = f2bf(spline_w[(size_t)(bi + 3) * NCOEF + c] * spline_s[bi + 3]);
            }
            *(ushort4*)&smem[FOFF_B + o * FSTR + qq * 4] = make_ushort4(r0, r1, r2, r3);
        }
        __syncthreads();
        #pragma unroll
        for (int ks = 0; ks < 2; ++ks) {
            int koff = ks * 32 + lquad * 8;
            bf16x8 af[4], bfr[4];
            #pragma unroll
            for (int mt = 0; mt < 4; ++mt)
                af[mt] = *(const bf16x8*)&smem[FOFF_A + (m0 + mt*16 + lrow) * FSTR + koff];
            #pragma unroll
            for (int nt = 0; nt < 4; ++nt)
                bfr[nt] = *(const bf16x8*)&smem[FOFF_B + (n0 + nt*16 + lrow) * FSTR + koff];
            #pragma unroll
            for (int mt = 0; mt < 4; ++mt)
                #pragma unroll
                for (int nt = 0; nt < 4; ++nt)
                    acc[mt][nt] = __builtin_amdgcn_mfma_f32_16x16x32_bf16(
                        af[mt], bfr[nt], acc[mt][nt], 0, 0, 0);
        }
        __syncthreads();
    }

    #pragma unroll
    for (int mt = 0; mt < 4; ++mt) {
        #pragma unroll
        for (int r = 0; r < 4; ++r) {
            int row = m0 + mt*16 + lquad*4 + r;
            int eg  = e_base + row;
            if (eg < NEDGES) {
                float* op = out + (size_t)eg * OUT_DIM + n0 + lrow;
                #pragma unroll
                for (int nt = 0; nt < 4; ++nt)
                    op[nt * 16] = acc[mt][nt][r];
            }
        }
    }
}

// ---------------- launch ----------------
extern "C" void kernel_launch(void* const* d_in, const int* in_sizes, int n_in,
                              void* d_out, int out_size, void* d_ws, size_t ws_size,
                              hipStream_t stream)
{
    const float* node_emb = (const float*)d_in[0];
    const float* ctx_emb  = (const float*)d_in[1];
    const int*   pair     = (const int*)d_in[2];
    const float* ctx_w    = (const float*)d_in[3];
    const float* ctx_b    = (const float*)d_in[4];
    const float* base_w   = (const float*)d_in[5];
    const float* spline_w = (const float*)d_in[6];
    const float* spline_s = (const float*)d_in[7];
    const float* grid     = (const float*)d_in[8];
    float* out = (float*)d_out;

    const int nblk = (NEDGES + BM2 - 1) / BM2;     // 782
    const size_t ctxwoff = 1572864u;               // after Wsw (96*256*32*2 B)
    const size_t xoff    = 2u * 1024u * 1024u;     // CtxB
    const size_t need = xoff + (size_t)NEDGES * 128 * sizeof(unsigned short);

    if (ws_size >= need) {
        unsigned short* Wsw   = (unsigned short*)d_ws;
        unsigned short* CtxwB = (unsigned short*)((char*)d_ws + ctxwoff);
        unsigned short* CtxB  = (unsigned short*)((char*)d_ws + xoff);
        prep_w2<<<OUT_DIM, IN_DIM, 0, stream>>>(base_w, spline_w, spline_s, Wsw);
        prep_ctxw<<<128, 64, 0, stream>>>(ctx_w, CtxwB);
        ctx_gemm<<<nblk, 512, 0, stream>>>(ctx_emb, CtxwB, ctx_b, CtxB);
        kan_gemm2<<<nblk, THR2, 0, stream>>>(Wsw, CtxB, node_emb, pair, grid, out);
    } else {
        fused_fallback<<<nblk, 512, 0, stream>>>(
            node_emb, ctx_emb, pair, ctx_w, ctx_b, base_w, spline_w, spline_s, grid, out);
    }
}

// Round 4
// 435.424 us; speedup vs baseline: 1.0407x; 1.0246x over previous
//
#include <hip/hip_runtime.h>

// ---------------- problem constants ----------------
#define NEDGES   100000
#define NODE_DIM 128
#define CTX_DIM  256
#define OUT_DIM  256
#define IN_DIM   384
#define NCOEF    7

// kan_gemm2 tiling: K' = i*8 + slot, slot0=silu, slot1..7=spline c=slot-1
#define BM2      128
#define BK2      32            // 4 x-cols * 8 slots
#define NCH2     96            // IN_DIM / 4
#define THR2     512           // 8 waves

typedef __bf16 bf16x8 __attribute__((ext_vector_type(8)));
typedef float  f32x4  __attribute__((ext_vector_type(4)));

static __device__ __forceinline__ unsigned short f2bf(float f) {
    unsigned int u = __float_as_uint(f);
    u += 0x7FFFu + ((u >> 16) & 1u);   // RNE
    return (unsigned short)(u >> 16);
}
static __device__ __forceinline__ float bf2f(unsigned short h) {
    return __uint_as_float(((unsigned int)h) << 16);
}
static __device__ __forceinline__ unsigned int pkbf(float a, float b) {
    unsigned int ua = __float_as_uint(a), ub = __float_as_uint(b);
    ua += 0x7FFFu + ((ua >> 16) & 1u);
    ub += 0x7FFFu + ((ub >> 16) & 1u);
    return (ua >> 16) | (ub & 0xFFFF0000u);
}
static __device__ __forceinline__ float silu(float x) {
    return x / (1.0f + __expf(-x));
}
// cardinal cubic B-spline (fallback path)
static __device__ __forceinline__ float n3(float t) {
    float d2 = t - 2.0f;
    float a  = fabsf(d2);
    float p1 = fmaf(fmaf(0.5f, a, -1.0f), d2 * d2, 0.66666667f);
    float dd = fmaxf(2.0f - a, 0.0f);
    float p2 = dd * dd * (dd * (1.0f / 6.0f));
    return a < 1.0f ? p1 : p2;
}

static __device__ __forceinline__ void glds16(const unsigned short* g, unsigned short* l) {
    __builtin_amdgcn_global_load_lds(
        (const __attribute__((address_space(1))) void*)g,
        (__attribute__((address_space(3))) void*)l, 16, 0, 0);
}

// =====================================================================
// W prep: chunk-major [96][256 o][32 k], granule-permuted for LDS banks.
// chunk ch = i>>2 covers x-cols i = ch*4..+3; granule (16B = 8 slots of
// one (o,i)) at index p = o*4 + (((o>>1) + (i&3)) & 3)
// =====================================================================
__global__ void prep_w2(const float* __restrict__ base_w,
                        const float* __restrict__ spline_w,
                        const float* __restrict__ spline_s,
                        unsigned short* __restrict__ Wsw)
{
    int o = blockIdx.x;          // 0..255
    int i = threadIdx.x;         // 0..383
    int bi = o * IN_DIM + i;
    float sc = spline_s[bi];
    const float* sw = spline_w + (size_t)bi * NCOEF;
    uint4 v;
    v.x = pkbf(base_w[bi], sw[0] * sc);
    v.y = pkbf(sw[1] * sc, sw[2] * sc);
    v.z = pkbf(sw[3] * sc, sw[4] * sc);
    v.w = pkbf(sw[5] * sc, sw[6] * sc);
    int ch = i >> 2, g8 = i & 3;
    int p  = o * 4 + (((o >> 1) + g8) & 3);
    *(uint4*)(Wsw + (size_t)ch * (OUT_DIM * BK2) + p * 8) = v;
}

// =====================================================================
// prep_ctxw: ctx_w [128 n][256 k] f32 -> bf16 row-major (L2-resident B
// operand, read directly by the fused ctx prologue — no per-block staging)
// =====================================================================
__global__ void prep_ctxw(const float* __restrict__ ctx_w,
                          unsigned short* __restrict__ B)
{
    int n  = blockIdx.x;         // 0..127
    int k4 = threadIdx.x;        // 0..63
    float4 v = *(const float4*)(ctx_w + (size_t)n * CTX_DIM + k4 * 4);
    *(uint2*)&B[(size_t)n * CTX_DIM + k4 * 4] =
        make_uint2(pkbf(v.x, v.y), pkbf(v.z, v.w));
}

// =====================================================================
// kan_gemm2 (FUSED): per-block ctx prologue (128x128x256 GEMM -> CtxB
// rows of this block, L2-hot), then main KAN GEMM with in-flight A gen.
// x sourced: subj/obj from node_emb (f32 gather), ctx from CtxB (bf16).
// dbuf A + dbuf B, one barrier per BK=32 chunk.
// =====================================================================
#define A2STR  40                          // 32 + 8 pad (ushorts)
#define A2SZ   (BM2 * A2STR)               // 5120
#define B2SZ   (OUT_DIM * BK2)             // 8192
#define OFF_A0 0
#define OFF_A1 A2SZ
#define OFF_B0 (2 * A2SZ)
#define OFF_B1 (2 * A2SZ + B2SZ)
#define LDS2   (2 * A2SZ + 2 * B2SZ)       // 26624 ush = 53248 B
#define CG_STR 72                          // ctx prologue A-stage stride
#define CG_ESTR 136                        // ctx prologue epilogue stride

// one x element -> 8 bf16 slots [silu | c0..c6], single b128 LDS write.
// spline: u=frac(t); 4 nonzero pieces Q0..Q3 positioned by 128-bit shift.
static __device__ __forceinline__ void gen_elem(
    float x, float hinv, float b0, unsigned short* dst)
{
    float sl = silu(x);
    unsigned short slh = f2bf(sl);
    float t  = fmaf(x, hinv, b0);
    float jf = floorf(t);
    int   j0 = (int)jf;
    float u  = t - jf;
    float u2 = u * u, u3 = u2 * u;
    float Q0 = u3 * 0.16666667f;
    float d  = 1.0f - u;
    float Q3 = d * d * d * 0.16666667f;
    float Q1 = fmaf(0.5f, u + u2 - u3, 0.16666667f);
    float Q2 = fmaf(0.5f, u3, 0.66666667f - u2);
    // payload slots ascending: [Q3 @ g=j0-2, Q2, Q1, Q0 @ g=j0+1]
    unsigned plo = pkbf(Q3, Q2);
    unsigned phi = pkbf(Q1, Q0);
    unsigned long long P = ((unsigned long long)phi << 32) | plo;
    int sh = (j0 << 4) - 32;
    unsigned a  = (unsigned)sh;
    unsigned na = 0u - a;
    unsigned long long lo =
        (a  < 64u) ? (P << (a  & 63u)) : ((na < 64u) ? (P >> (na & 63u)) : 0ull);
    unsigned b2 = a - 64u;
    unsigned nb = 0u - b2;
    unsigned long long hi =
        (b2 < 64u) ? (P << (b2 & 63u)) : ((nb < 64u) ? (P >> (nb & 63u)) : 0ull);
    lo = (lo & ~0xFFFFull) | (unsigned long long)slh;   // slot0 = silu
    uint4 w;
    w.x = (unsigned)lo; w.y = (unsigned)(lo >> 32);
    w.z = (unsigned)hi; w.w = (unsigned)(hi >> 32);
    *(uint4*)dst = w;
}

// x fetch for chunk ch (wave-uniform branch: ch is uniform)
static __device__ __forceinline__ float fetchx(
    const float* ps, const float* po, const unsigned short* pc, int ch)
{
    if (ch < 32) return ps[ch << 2];
    if (ch < 64) return po[(ch - 32) << 2];
    return bf2f(pc[(ch - 64) << 2]);
}

__global__ __launch_bounds__(THR2, 4)
void kan_gemm2(const unsigned short* __restrict__ Wsw,
               const float* __restrict__ ctx_emb,
               const unsigned short* __restrict__ ctxwB,
               const float* __restrict__ ctx_b,
               unsigned short* __restrict__ CtxB,
               const float* __restrict__ node_emb,
               const int*   __restrict__ pair,
               const float* __restrict__ grid,
               float* __restrict__ out)
{
    __shared__ unsigned short smem[LDS2];
    const int tid    = threadIdx.x;
    const int e_base = blockIdx.x * BM2;
    const int wid    = tid >> 6;
    const int lan    = tid & 63;
    const int lrow   = lan & 15;
    const int lquad  = lan >> 4;
    const int m0     = (wid & 1) * 64;
    const int n0     = (wid >> 1) * 64;

    // ---------- fused ctx prologue: ctx tile for this block's 128 rows ----
    {
        f32x4 cacc[4][2];
        #pragma unroll
        for (int a = 0; a < 4; ++a)
            #pragma unroll
            for (int b = 0; b < 2; ++b) { f32x4 z = {0.f,0.f,0.f,0.f}; cacc[a][b] = z; }
        const int cn0 = (wid >> 1) * 32;   // ctx N-quarter (N=128)

        // stage kc=0 into buf0
        #pragma unroll
        for (int it = 0; it < 4; ++it) {
            int id = it * THR2 + tid;
            int r  = id >> 4;
            int c4 = id & 15;
            int eg = e_base + r; if (eg >= NEDGES) eg = NEDGES - 1;
            float4 v = *(const float4*)(ctx_emb + (size_t)eg * CTX_DIM + c4 * 4);
            *(uint2*)&smem[r * CG_STR + c4 * 4] = make_uint2(pkbf(v.x, v.y), pkbf(v.z, v.w));
        }
        __syncthreads();

        for (int kc = 0; kc < 4; ++kc) {
            if (kc + 1 < 4) {
                unsigned short* nb = smem + ((kc + 1) & 1) * (128 * CG_STR);
                #pragma unroll
                for (int it = 0; it < 4; ++it) {
                    int id = it * THR2 + tid;
                    int r  = id >> 4;
                    int c4 = id & 15;
                    int eg = e_base + r; if (eg >= NEDGES) eg = NEDGES - 1;
                    float4 v = *(const float4*)(ctx_emb + (size_t)eg * CTX_DIM + (kc + 1) * 64 + c4 * 4);
                    *(uint2*)&nb[r * CG_STR + c4 * 4] = make_uint2(pkbf(v.x, v.y), pkbf(v.z, v.w));
                }
            }
            const unsigned short* sa = smem + (kc & 1) * (128 * CG_STR);
            #pragma unroll
            for (int ks = 0; ks < 2; ++ks) {
                int koff = ks * 32 + lquad * 8;
                bf16x8 caf[4], cbf[2];
                #pragma unroll
                for (int mt = 0; mt < 4; ++mt)
                    caf[mt] = *(const bf16x8*)&sa[(m0 + mt*16 + lrow) * CG_STR + koff];
                #pragma unroll
                for (int nt = 0; nt < 2; ++nt)
                    cbf[nt] = *(const bf16x8*)&ctxwB[(size_t)(cn0 + nt*16 + lrow) * CTX_DIM + kc * 64 + koff];
                #pragma unroll
                for (int mt = 0; mt < 4; ++mt)
                    #pragma unroll
                    for (int nt = 0; nt < 2; ++nt)
                        cacc[mt][nt] = __builtin_amdgcn_mfma_f32_16x16x32_bf16(
                            caf[mt], cbf[nt], cacc[mt][nt], 0, 0, 0);
            }
            __syncthreads();
        }

        // epilogue: +bias, stage bf16 in LDS, coalesced 8B writes to CtxB
        #pragma unroll
        for (int nt = 0; nt < 2; ++nt) {
            int col = cn0 + nt * 16 + lrow;
            float cb = ctx_b[col];
            #pragma unroll
            for (int mt = 0; mt < 4; ++mt)
                #pragma unroll
                for (int r = 0; r < 4; ++r) {
                    int row = m0 + mt * 16 + lquad * 4 + r;
                    smem[row * CG_ESTR + col] = f2bf(cacc[mt][nt][r] + cb);
                }
        }
        __syncthreads();
        #pragma unroll
        for (int it = 0; it < 8; ++it) {
            int id  = it * THR2 + tid;      // 128 rows x 32 uint2-groups
            int row = id >> 5;
            int g   = id & 31;
            int eg  = e_base + row; if (eg >= NEDGES) eg = NEDGES - 1;
            *(uint2*)&CtxB[(size_t)eg * 128 + g * 4] = *(uint2*)&smem[row * CG_ESTR + g * 4];
        }
        __syncthreads();   // smem free + CtxB stores drained (barrier vmcnt(0))
    }

    // ---------- main KAN GEMM ----------
    const float g0   = grid[0];
    const float hinv = 1.0f / (grid[1] - grid[0]);
    const float b0   = -g0 * hinv;

    // gen assignment: one elem/thread/chunk
    const int grow = tid >> 2;           // 0..127
    const int gcol = tid & 3;
    int geg = e_base + grow; if (geg >= NEDGES) geg = NEDGES - 1;
    const int nsub = pair[geg * 2 + 0];
    const int nobj = pair[geg * 2 + 1];
    const float* ps = node_emb + (size_t)nsub * NODE_DIM + gcol;
    const float* po = node_emb + (size_t)nobj * NODE_DIM + gcol;
    const unsigned short* pc = CtxB + (size_t)geg * 128 + gcol;
    const unsigned awr = grow * A2STR + gcol * 8;

    f32x4 acc[4][4];
    #pragma unroll
    for (int a = 0; a < 4; ++a)
        #pragma unroll
        for (int b = 0; b < 4; ++b) { f32x4 z = {0.f,0.f,0.f,0.f}; acc[a][b] = z; }

    float xc = fetchx(ps, po, pc, 0);
    float xn = fetchx(ps, po, pc, 1);

    // prologue: B(0) DMA + A(0) gen
    #pragma unroll
    for (int it = 0; it < 2; ++it) {
        int id = it * THR2 + tid;
        glds16(Wsw + id * 8, &smem[OFF_B0 + id * 8]);
    }
    gen_elem(xc, hinv, b0, &smem[OFF_A0 + awr]);
    __syncthreads();

    for (int kb = 0; kb < NCH2; ++kb) {
        const int cur = kb & 1;
        if (kb + 1 < NCH2) {
            float xh = xn;
            if (kb + 2 < NCH2) xn = fetchx(ps, po, pc, kb + 2);  // issue early
            const unsigned short* wc = Wsw + (size_t)(kb + 1) * B2SZ;
            unsigned boff = cur ? OFF_B0 : OFF_B1;   // next buffer
            #pragma unroll
            for (int it = 0; it < 2; ++it) {
                int id = it * THR2 + tid;
                glds16(wc + id * 8, &smem[boff + id * 8]);
            }
            gen_elem(xh, hinv, b0, &smem[(cur ? OFF_A0 : OFF_A1) + awr]);
        }
        // MFMA on current buffers
        const unsigned ab = cur ? OFF_A1 : OFF_A0;
        const unsigned bb = cur ? OFF_B1 : OFF_B0;
        bf16x8 af[4], bfr[4];
        #pragma unroll
        for (int mt = 0; mt < 4; ++mt)
            af[mt] = *(const bf16x8*)&smem[ab + (m0 + mt*16 + lrow) * A2STR + lquad * 8];
        #pragma unroll
        for (int nt = 0; nt < 4; ++nt) {
            int n = n0 + nt * 16 + lrow;
            bfr[nt] = *(const bf16x8*)&smem[bb + n * 32 + ((((n >> 1) + lquad) & 3) << 3)];
        }
        #pragma unroll
        for (int mt = 0; mt < 4; ++mt)
            #pragma unroll
            for (int nt = 0; nt < 4; ++nt)
                acc[mt][nt] = __builtin_amdgcn_mfma_f32_16x16x32_bf16(
                    af[mt], bfr[nt], acc[mt][nt], 0, 0, 0);
        __syncthreads();
    }

    // epilogue: C row = edge (m), col = out (n)
    #pragma unroll
    for (int mt = 0; mt < 4; ++mt) {
        #pragma unroll
        for (int r = 0; r < 4; ++r) {
            int row = m0 + mt * 16 + lquad * 4 + r;
            int eg  = e_base + row;
            if (eg < NEDGES) {
                float* op = out + (size_t)eg * OUT_DIM + n0 + lrow;
                #pragma unroll
                for (int nt = 0; nt < 4; ++nt)
                    op[nt * 16] = acc[mt][nt][r];
            }
        }
    }
}

// =====================================================================
// FALLBACK (no workspace): round-1 fused kernel, correctness-only
// =====================================================================
#define XSTR 392
#define FSTR 72
#define FOFF_X 0
#define FOFF_A (128 * XSTR)
#define FOFF_B (FOFF_A + 128 * FSTR)
#define FLDS (FOFF_B + OUT_DIM * FSTR)

__global__ __launch_bounds__(512, 2)
void fused_fallback(const float* __restrict__ node_emb,
                    const float* __restrict__ ctx_emb,
                    const int*   __restrict__ pair,
                    const float* __restrict__ ctx_w,
                    const float* __restrict__ ctx_b,
                    const float* __restrict__ base_w,
                    const float* __restrict__ spline_w,
                    const float* __restrict__ spline_s,
                    const float* __restrict__ grid,
                    float* __restrict__ out)
{
    __shared__ unsigned short smem[FLDS];
    const int tid    = threadIdx.x;
    const int e_base = blockIdx.x * 128;
    const int wid    = tid >> 6;
    const int lan    = tid & 63;
    const int lrow   = lan & 15;
    const int lquad  = lan >> 4;

    #pragma unroll
    for (int it = 0; it < 16; ++it) {
        int id    = it * 512 + tid;
        int lane4 = id & 31;
        int e     = (id >> 5) & 127;
        int which = id >> 12;
        int eg = e_base + e; if (eg >= NEDGES) eg = NEDGES - 1;
        int node = pair[eg * 2 + which];
        const float4 v = *(const float4*)(node_emb + (size_t)node * NODE_DIM + lane4 * 4);
        *(ushort4*)&smem[FOFF_X + e * XSTR + which * NODE_DIM + lane4 * 4] =
            make_ushort4(f2bf(v.x), f2bf(v.y), f2bf(v.z), f2bf(v.w));
    }
    {
        f32x4 cacc[4][2];
        #pragma unroll
        for (int a = 0; a < 4; ++a)
            #pragma unroll
            for (int b = 0; b < 2; ++b) { f32x4 z = {0.f,0.f,0.f,0.f}; cacc[a][b] = z; }
        const int m0 = (wid & 1) * 64;
        const int n0 = (wid >> 1) * 32;
        for (int kc = 0; kc < 4; ++kc) {
            #pragma unroll
            for (int it = 0; it < 4; ++it) {
                int id = it * 512 + tid;
                int r  = id >> 4;
                int c4 = id & 15;
                int eg = e_base + r; if (eg >= NEDGES) eg = NEDGES - 1;
                float4 v = *(const float4*)(ctx_emb + (size_t)eg * CTX_DIM + kc * 64 + c4 * 4);
                *(ushort4*)&smem[FOFF_A + r * FSTR + c4 * 4] =
                    make_ushort4(f2bf(v.x), f2bf(v.y), f2bf(v.z), f2bf(v.w));
                float4 w = *(const float4*)(ctx_w + (size_t)r * CTX_DIM + kc * 64 + c4 * 4);
                *(ushort4*)&smem[FOFF_B + r * FSTR + c4 * 4] =
                    make_ushort4(f2bf(w.x), f2bf(w.y), f2bf(w.z), f2bf(w.w));
            }
            __syncthreads();
            #pragma unroll
            for (int ks = 0; ks < 2; ++ks) {
                int koff = ks * 32 + lquad * 8;
                bf16x8 af[4], bfr[2];
                #pragma unroll
                for (int mt = 0; mt < 4; ++mt)
                    af[mt] = *(const bf16x8*)&smem[FOFF_A + (m0 + mt*16 + lrow) * FSTR + koff];
                #pragma unroll
                for (int nt = 0; nt < 2; ++nt)
                    bfr[nt] = *(const bf16x8*)&smem[FOFF_B + (n0 + nt*16 + lrow) * FSTR + koff];
                #pragma unroll
                for (int mt = 0; mt < 4; ++mt)
                    #pragma unroll
                    for (int nt = 0; nt < 2; ++nt)
                        cacc[mt][nt] = __builtin_amdgcn_mfma_f32_16x16x32_bf16(
                            af[mt], bfr[nt], cacc[mt][nt], 0, 0, 0);
            }
            __syncthreads();
        }
        #pragma unroll
        for (int mt = 0; mt < 4; ++mt)
            #pragma unroll
            for (int nt = 0; nt < 2; ++nt)
                #pragma unroll
                for (int r = 0; r < 4; ++r) {
                    int row = m0 + mt*16 + lquad*4 + r;
                    int col = n0 + nt*16 + lrow;
                    smem[FOFF_X + row * XSTR + 256 + col] = f2bf(cacc[mt][nt][r] + ctx_b[col]);
                }
    }
    __syncthreads();

    const float g0   = grid[0];
    const float hinv = 1.0f / (grid[1] - grid[0]);

    f32x4 acc[4][4];
    #pragma unroll
    for (int a = 0; a < 4; ++a)
        #pragma unroll
        for (int b = 0; b < 4; ++b) { f32x4 z = {0.f,0.f,0.f,0.f}; acc[a][b] = z; }

    const int m0 = (wid & 1) * 64;
    const int n0 = (wid >> 1) * 64;

    for (int kb = 0; kb < 48; ++kb) {
        const int seg = kb / 6;
        const int i0  = (kb - seg * 6) * 64;
        #pragma unroll
        for (int it = 0; it < 4; ++it) {
            int id = it * 512 + tid;
            int e  = id >> 4;
            int qq = id & 15;
            ushort4 xv = *(const ushort4*)&smem[FOFF_X + e * XSTR + i0 + qq * 4];
            float x0 = bf2f(xv.x), x1 = bf2f(xv.y), x2 = bf2f(xv.z), x3 = bf2f(xv.w);
            unsigned short r0, r1, r2, r3;
            if (seg == 0) {
                r0 = f2bf(silu(x0)); r1 = f2bf(silu(x1));
                r2 = f2bf(silu(x2)); r3 = f2bf(silu(x3));
            } else {
                const float cf = (float)(seg - 1);
                r0 = f2bf(n3((x0 - g0) * hinv - cf));
                r1 = f2bf(n3((x1 - g0) * hinv - cf));
                r2 = f2bf(n3((x2 - g0) * hinv - cf));
                r3 = f2bf(n3((x3 - g0) * hinv - cf));
            }
            *(ushort4*)&smem[FOFF_A + e * FSTR + qq * 4] = make_ushort4(r0, r1, r2, r3);
        }
        #pragma unroll
        for (int it = 0; it < 4; ++it) {
            int id = it * 512 + tid;
            int o  = id >> 4;
            int qq = id & 15;
            unsigned short r0, r1, r2, r3;
            if (seg == 0) {
                const float4 w = *(const float4*)(base_w + (size_t)o * IN_DIM + i0 + qq * 4);
                r0 = f2bf(w.x); r1 = f2bf(w.y); r2 = f2bf(w.z); r3 = f2bf(w.w);
            } else {
                int c  = seg - 1;
                int bi = o * IN_DIM + i0 + qq * 4;
                r0 = f2bf(spline_w[(size_t)(bi    ) * NCOEF + c] * spline_s[bi    ]);
                r1 = f2bf(spline_w[(size_t)(bi + 1) * NCOEF + c] * spline_s[bi + 1]);
                r2 = f2bf(spline_w[(size_t)(bi + 2) * NCOEF + c] * spline_s[bi + 2]);
                r3 = f2bf(spline_w[(size_t)(bi + 3) * NCOEF + c] * spline_s[bi + 3]);
            }
            *(ushort4*)&smem[FOFF_B + o * FSTR + qq * 4] = make_ushort4(r0, r1, r2, r3);
        }
        __syncthreads();
        #pragma unroll
        for (int ks = 0; ks < 2; ++ks) {
            int koff = ks * 32 + lquad * 8;
            bf16x8 af[4], bfr[4];
            #pragma unroll
            for (int mt = 0; mt < 4; ++mt)
                af[mt] = *(const bf16x8*)&smem[FOFF_A + (m0 + mt*16 + lrow) * FSTR + koff];
            #pragma unroll
            for (int nt = 0; nt < 4; ++nt)
                bfr[nt] = *(const bf16x8*)&smem[FOFF_B + (n0 + nt*16 + lrow) * FSTR + koff];
            #pragma unroll
            for (int mt = 0; mt < 4; ++mt)
                #pragma unroll
                for (int nt = 0; nt < 4; ++nt)
                    acc[mt][nt] = __builtin_amdgcn_mfma_f32_16x16x32_bf16(
                        af[mt], bfr[nt], acc[mt][nt], 0, 0, 0);
        }
        __syncthreads();
    }

    #pragma unroll
    for (int mt = 0; mt < 4; ++mt) {
        #pragma unroll
        for (int r = 0; r < 4; ++r) {
            int row = m0 + mt*16 + lquad*4 + r;
            int eg  = e_base + row;
            if (eg < NEDGES) {
                float* op = out + (size_t)eg * OUT_DIM + n0 + lrow;
                #pragma unroll
                for (int nt = 0; nt < 4; ++nt)
                    op[nt * 16] = acc[mt][nt][r];
            }
        }
    }
}

// ---------------- launch ----------------
extern "C" void kernel_launch(void* const* d_in, const int* in_sizes, int n_in,
                              void* d_out, int out_size, void* d_ws, size_t ws_size,
                              hipStream_t stream)
{
    const float* node_emb = (const float*)d_in[0];
    const float* ctx_emb  = (const float*)d_in[1];
    const int*   pair     = (const int*)d_in[2];
    const float* ctx_w    = (const float*)d_in[3];
    const float* ctx_b    = (const float*)d_in[4];
    const float* base_w   = (const float*)d_in[5];
    const float* spline_w = (const float*)d_in[6];
    const float* spline_s = (const float*)d_in[7];
    const float* grid     = (const float*)d_in[8];
    float* out = (float*)d_out;

    const int nblk = (NEDGES + BM2 - 1) / BM2;     // 782
    const size_t ctxwoff = 1572864u;               // after Wsw (96*256*32*2 B)
    const size_t xoff    = 2u * 1024u * 1024u;     // CtxB
    const size_t need = xoff + (size_t)NEDGES * 128 * sizeof(unsigned short);

    if (ws_size >= need) {
        unsigned short* Wsw   = (unsigned short*)d_ws;
        unsigned short* CtxwB = (unsigned short*)((char*)d_ws + ctxwoff);
        unsigned short* CtxB  = (unsigned short*)((char*)d_ws + xoff);
        prep_w2<<<OUT_DIM, IN_DIM, 0, stream>>>(base_w, spline_w, spline_s, Wsw);
        prep_ctxw<<<128, 64, 0, stream>>>(ctx_w, CtxwB);
        kan_gemm2<<<nblk, THR2, 0, stream>>>(
            Wsw, ctx_emb, CtxwB, ctx_b, CtxB, node_emb, pair, grid, out);
    } else {
        fused_fallback<<<nblk, 512, 0, stream>>>(
            node_emb, ctx_emb, pair, ctx_w, ctx_b, base_w, spline_w, spline_s, grid, out);
    }
}

// Round 5
// 433.552 us; speedup vs baseline: 1.0452x; 1.0043x over previous
//
#include <hip/hip_runtime.h>

// ---------------- problem constants ----------------
#define NEDGES   100000
#define NODE_DIM 128
#define CTX_DIM  256
#define OUT_DIM  256
#define IN_DIM   384
#define NCOEF    7

// kan_gemm2 tiling: K' = i*8 + slot, slot0=silu, slot1..7=spline c=slot-1
#define BM2      128
#define BK2      32            // 4 x-cols * 8 slots
#define NCH2     96            // IN_DIM / 4
#define THR2     512           // 8 waves

typedef __bf16 bf16x8 __attribute__((ext_vector_type(8)));
typedef float  f32x4  __attribute__((ext_vector_type(4)));

static __device__ __forceinline__ unsigned short f2bf(float f) {
    unsigned int u = __float_as_uint(f);
    u += 0x7FFFu + ((u >> 16) & 1u);   // RNE
    return (unsigned short)(u >> 16);
}
static __device__ __forceinline__ float bf2f(unsigned short h) {
    return __uint_as_float(((unsigned int)h) << 16);
}
static __device__ __forceinline__ unsigned int pkbf(float a, float b) {
    unsigned int ua = __float_as_uint(a), ub = __float_as_uint(b);
    ua += 0x7FFFu + ((ua >> 16) & 1u);
    ub += 0x7FFFu + ((ub >> 16) & 1u);
    return (ua >> 16) | (ub & 0xFFFF0000u);
}
static __device__ __forceinline__ float silu(float x) {
    return x / (1.0f + __expf(-x));
}
// cardinal cubic B-spline (fallback path)
static __device__ __forceinline__ float n3(float t) {
    float d2 = t - 2.0f;
    float a  = fabsf(d2);
    float p1 = fmaf(fmaf(0.5f, a, -1.0f), d2 * d2, 0.66666667f);
    float dd = fmaxf(2.0f - a, 0.0f);
    float p2 = dd * dd * (dd * (1.0f / 6.0f));
    return a < 1.0f ? p1 : p2;
}

static __device__ __forceinline__ void glds16(const unsigned short* g, unsigned short* l) {
    __builtin_amdgcn_global_load_lds(
        (const __attribute__((address_space(1))) void*)g,
        (__attribute__((address_space(3))) void*)l, 16, 0, 0);
}

// =====================================================================
// W prep: chunk-major [96][256 o][32 k], granule-permuted for LDS banks.
// chunk ch = i>>2 covers x-cols i = ch*4..+3; granule (16B = 8 slots of
// one (o,i)) at index p = o*4 + (((o>>1) + (i&3)) & 3)
// =====================================================================
__global__ void prep_w2(const float* __restrict__ base_w,
                        const float* __restrict__ spline_w,
                        const float* __restrict__ spline_s,
                        unsigned short* __restrict__ Wsw)
{
    int o = blockIdx.x;          // 0..255
    int i = threadIdx.x;         // 0..383
    int bi = o * IN_DIM + i;
    float sc = spline_s[bi];
    const float* sw = spline_w + (size_t)bi * NCOEF;
    uint4 v;
    v.x = pkbf(base_w[bi], sw[0] * sc);
    v.y = pkbf(sw[1] * sc, sw[2] * sc);
    v.z = pkbf(sw[3] * sc, sw[4] * sc);
    v.w = pkbf(sw[5] * sc, sw[6] * sc);
    int ch = i >> 2, g8 = i & 3;
    int p  = o * 4 + (((o >> 1) + g8) & 3);
    *(uint4*)(Wsw + (size_t)ch * (OUT_DIM * BK2) + p * 8) = v;
}

// =====================================================================
// prep_ctxw: ctx_w [128 n][256 k] f32 -> bf16 row-major (L2-resident B
// operand, read directly by the fused ctx prologue — no per-block staging)
// =====================================================================
__global__ void prep_ctxw(const float* __restrict__ ctx_w,
                          unsigned short* __restrict__ B)
{
    int n  = blockIdx.x;         // 0..127
    int k4 = threadIdx.x;        // 0..63
    float4 v = *(const float4*)(ctx_w + (size_t)n * CTX_DIM + k4 * 4);
    *(uint2*)&B[(size_t)n * CTX_DIM + k4 * 4] =
        make_uint2(pkbf(v.x, v.y), pkbf(v.z, v.w));
}

// =====================================================================
// kan_gemm2 (FUSED): per-block ctx prologue (128x128x256 GEMM -> CtxB
// rows of this block, L2-hot), then main KAN GEMM with in-flight A gen.
// Main loop: 3-deep B pipeline (DMA k+2 issued at iter k), raw s_barrier
// with counted vmcnt(3) — B-DMA never drained at the barrier it crosses.
// =====================================================================
#define A2STR  40                          // 32 + 8 pad (ushorts)
#define A2SZ   (BM2 * A2STR)               // 5120
#define B2SZ   (OUT_DIM * BK2)             // 8192
#define OFF_A0 0
#define OFF_A1 A2SZ
#define OFF_B0 (2 * A2SZ)
#define LDS2   (2 * A2SZ + 3 * B2SZ)       // 34816 ush = 69632 B -> 2 blk/CU
#define CG_STR 72                          // ctx prologue A-stage stride
#define CG_ESTR 136                        // ctx prologue epilogue stride

// one x element -> 8 bf16 slots [silu | c0..c6], single b128 LDS write.
// spline: u=frac(t); 4 nonzero pieces Q0..Q3 positioned by 128-bit shift.
static __device__ __forceinline__ void gen_elem(
    float x, float hinv, float b0, unsigned short* dst)
{
    float sl = silu(x);
    unsigned short slh = f2bf(sl);
    float t  = fmaf(x, hinv, b0);
    float jf = floorf(t);
    int   j0 = (int)jf;
    float u  = t - jf;
    float u2 = u * u, u3 = u2 * u;
    float Q0 = u3 * 0.16666667f;
    float d  = 1.0f - u;
    float Q3 = d * d * d * 0.16666667f;
    float Q1 = fmaf(0.5f, u + u2 - u3, 0.16666667f);
    float Q2 = fmaf(0.5f, u3, 0.66666667f - u2);
    // payload slots ascending: [Q3 @ g=j0-2, Q2, Q1, Q0 @ g=j0+1]
    unsigned plo = pkbf(Q3, Q2);
    unsigned phi = pkbf(Q1, Q0);
    unsigned long long P = ((unsigned long long)phi << 32) | plo;
    int sh = (j0 << 4) - 32;
    unsigned a  = (unsigned)sh;
    unsigned na = 0u - a;
    unsigned long long lo =
        (a  < 64u) ? (P << (a  & 63u)) : ((na < 64u) ? (P >> (na & 63u)) : 0ull);
    unsigned b2 = a - 64u;
    unsigned nb = 0u - b2;
    unsigned long long hi =
        (b2 < 64u) ? (P << (b2 & 63u)) : ((nb < 64u) ? (P >> (nb & 63u)) : 0ull);
    lo = (lo & ~0xFFFFull) | (unsigned long long)slh;   // slot0 = silu
    uint4 w;
    w.x = (unsigned)lo; w.y = (unsigned)(lo >> 32);
    w.z = (unsigned)hi; w.w = (unsigned)(hi >> 32);
    *(uint4*)dst = w;
}

// x fetch for chunk ch (wave-uniform branch: ch is uniform)
static __device__ __forceinline__ float fetchx(
    const float* ps, const float* po, const unsigned short* pc, int ch)
{
    if (ch < 32) return ps[ch << 2];
    if (ch < 64) return po[(ch - 32) << 2];
    return bf2f(pc[(ch - 64) << 2]);
}

__global__ __launch_bounds__(THR2, 4)
void kan_gemm2(const unsigned short* __restrict__ Wsw,
               const float* __restrict__ ctx_emb,
               const unsigned short* __restrict__ ctxwB,
               const float* __restrict__ ctx_b,
               unsigned short* __restrict__ CtxB,
               const float* __restrict__ node_emb,
               const int*   __restrict__ pair,
               const float* __restrict__ grid,
               float* __restrict__ out)
{
    __shared__ unsigned short smem[LDS2];
    const int tid    = threadIdx.x;
    const int e_base = blockIdx.x * BM2;
    const int wid    = tid >> 6;
    const int lan    = tid & 63;
    const int lrow   = lan & 15;
    const int lquad  = lan >> 4;
    const int m0     = (wid & 1) * 64;
    const int n0     = (wid >> 1) * 64;

    // ---------- fused ctx prologue: ctx tile for this block's 128 rows ----
    {
        f32x4 cacc[4][2];
        #pragma unroll
        for (int a = 0; a < 4; ++a)
            #pragma unroll
            for (int b = 0; b < 2; ++b) { f32x4 z = {0.f,0.f,0.f,0.f}; cacc[a][b] = z; }
        const int cn0 = (wid >> 1) * 32;   // ctx N-quarter (N=128)

        // stage kc=0 into buf0
        #pragma unroll
        for (int it = 0; it < 4; ++it) {
            int id = it * THR2 + tid;
            int r  = id >> 4;
            int c4 = id & 15;
            int eg = e_base + r; if (eg >= NEDGES) eg = NEDGES - 1;
            float4 v = *(const float4*)(ctx_emb + (size_t)eg * CTX_DIM + c4 * 4);
            *(uint2*)&smem[r * CG_STR + c4 * 4] = make_uint2(pkbf(v.x, v.y), pkbf(v.z, v.w));
        }
        __syncthreads();

        for (int kc = 0; kc < 4; ++kc) {
            if (kc + 1 < 4) {
                unsigned short* nb = smem + ((kc + 1) & 1) * (128 * CG_STR);
                #pragma unroll
                for (int it = 0; it < 4; ++it) {
                    int id = it * THR2 + tid;
                    int r  = id >> 4;
                    int c4 = id & 15;
                    int eg = e_base + r; if (eg >= NEDGES) eg = NEDGES - 1;
                    float4 v = *(const float4*)(ctx_emb + (size_t)eg * CTX_DIM + (kc + 1) * 64 + c4 * 4);
                    *(uint2*)&nb[r * CG_STR + c4 * 4] = make_uint2(pkbf(v.x, v.y), pkbf(v.z, v.w));
                }
            }
            const unsigned short* sa = smem + (kc & 1) * (128 * CG_STR);
            #pragma unroll
            for (int ks = 0; ks < 2; ++ks) {
                int koff = ks * 32 + lquad * 8;
                bf16x8 caf[4], cbf[2];
                #pragma unroll
                for (int mt = 0; mt < 4; ++mt)
                    caf[mt] = *(const bf16x8*)&sa[(m0 + mt*16 + lrow) * CG_STR + koff];
                #pragma unroll
                for (int nt = 0; nt < 2; ++nt)
                    cbf[nt] = *(const bf16x8*)&ctxwB[(size_t)(cn0 + nt*16 + lrow) * CTX_DIM + kc * 64 + koff];
                #pragma unroll
                for (int mt = 0; mt < 4; ++mt)
                    #pragma unroll
                    for (int nt = 0; nt < 2; ++nt)
                        cacc[mt][nt] = __builtin_amdgcn_mfma_f32_16x16x32_bf16(
                            caf[mt], cbf[nt], cacc[mt][nt], 0, 0, 0);
            }
            __syncthreads();
        }

        // epilogue: +bias, stage bf16 in LDS, coalesced 8B writes to CtxB
        #pragma unroll
        for (int nt = 0; nt < 2; ++nt) {
            int col = cn0 + nt * 16 + lrow;
            float cb = ctx_b[col];
            #pragma unroll
            for (int mt = 0; mt < 4; ++mt)
                #pragma unroll
                for (int r = 0; r < 4; ++r) {
                    int row = m0 + mt * 16 + lquad * 4 + r;
                    smem[row * CG_ESTR + col] = f2bf(cacc[mt][nt][r] + cb);
                }
        }
        __syncthreads();
        #pragma unroll
        for (int it = 0; it < 8; ++it) {
            int id  = it * THR2 + tid;      // 128 rows x 32 uint2-groups
            int row = id >> 5;
            int g   = id & 31;
            int eg  = e_base + row; if (eg >= NEDGES) eg = NEDGES - 1;
            *(uint2*)&CtxB[(size_t)eg * 128 + g * 4] = *(uint2*)&smem[row * CG_ESTR + g * 4];
        }
        __syncthreads();   // smem free + CtxB stores drained (barrier vmcnt(0))
    }

    // ---------- main KAN GEMM ----------
    const float g0   = grid[0];
    const float hinv = 1.0f / (grid[1] - grid[0]);
    const float b0   = -g0 * hinv;

    // gen assignment: one elem/thread/chunk
    const int grow = tid >> 2;           // 0..127
    const int gcol = tid & 3;
    int geg = e_base + grow; if (geg >= NEDGES) geg = NEDGES - 1;
    const int nsub = pair[geg * 2 + 0];
    const int nobj = pair[geg * 2 + 1];
    const float* ps = node_emb + (size_t)nsub * NODE_DIM + gcol;
    const float* po = node_emb + (size_t)nobj * NODE_DIM + gcol;
    const unsigned short* pc = CtxB + (size_t)geg * 128 + gcol;
    const unsigned awr = grow * A2STR + gcol * 8;

    f32x4 acc[4][4];
    #pragma unroll
    for (int a = 0; a < 4; ++a)
        #pragma unroll
        for (int b = 0; b < 4; ++b) { f32x4 z = {0.f,0.f,0.f,0.f}; acc[a][b] = z; }

    float xc = fetchx(ps, po, pc, 0);
    float xn = fetchx(ps, po, pc, 1);

    // rotating B triple-buffer offsets
    unsigned bcur = OFF_B0, bnxt = OFF_B0 + B2SZ, bnx2 = OFF_B0 + 2 * B2SZ;

    // prologue: B(0)+B(1) DMA + A(0) gen; leave B(1) in flight across barrier
    #pragma unroll
    for (int it = 0; it < 2; ++it) {
        int id = it * THR2 + tid;
        glds16(Wsw + id * 8, &smem[bcur + id * 8]);
    }
    #pragma unroll
    for (int it = 0; it < 2; ++it) {
        int id = it * THR2 + tid;
        glds16(Wsw + B2SZ + id * 8, &smem[bnxt + id * 8]);
    }
    gen_elem(xc, hinv, b0, &smem[OFF_A0 + awr]);
    asm volatile("s_waitcnt lgkmcnt(0)\n\ts_waitcnt vmcnt(2)" ::: "memory");
    __builtin_amdgcn_s_barrier();
    asm volatile("" ::: "memory");

    for (int kb = 0; kb < NCH2; ++kb) {
        const int cur = kb & 1;
        float xh = xn;
        if (kb + 2 < NCH2) {
            xn = fetchx(ps, po, pc, kb + 2);          // 1 vmem load
            const unsigned short* wc = Wsw + (size_t)(kb + 2) * B2SZ;
            #pragma unroll
            for (int it = 0; it < 2; ++it) {          // 2 vmem(->LDS) loads
                int id = it * THR2 + tid;
                glds16(wc + id * 8, &smem[bnx2 + id * 8]);
            }
        }
        if (kb + 1 < NCH2)
            gen_elem(xh, hinv, b0, &smem[(cur ? OFF_A0 : OFF_A1) + awr]);

        // MFMA on current buffers
        const unsigned ab = cur ? OFF_A1 : OFF_A0;
        bf16x8 af[4], bfr[4];
        #pragma unroll
        for (int mt = 0; mt < 4; ++mt)
            af[mt] = *(const bf16x8*)&smem[ab + (m0 + mt*16 + lrow) * A2STR + lquad * 8];
        #pragma unroll
        for (int nt = 0; nt < 4; ++nt) {
            int n = n0 + nt * 16 + lrow;
            bfr[nt] = *(const bf16x8*)&smem[bcur + n * 32 + ((((n >> 1) + lquad) & 3) << 3)];
        }
        #pragma unroll
        for (int mt = 0; mt < 4; ++mt)
            #pragma unroll
            for (int nt = 0; nt < 4; ++nt)
                acc[mt][nt] = __builtin_amdgcn_mfma_f32_16x16x32_bf16(
                    af[mt], bfr[nt], acc[mt][nt], 0, 0, 0);

        if (kb + 1 < NCH2) {
            // drain: all of last iter's loads (incl. B(kb+1) DMA) complete;
            // this iter's 3 loads (B(kb+2) DMA x2 + x-fetch) stay in flight.
            if (kb + 2 < NCH2)
                asm volatile("s_waitcnt lgkmcnt(0)\n\ts_waitcnt vmcnt(3)" ::: "memory");
            else
                asm volatile("s_waitcnt lgkmcnt(0)\n\ts_waitcnt vmcnt(0)" ::: "memory");
            __builtin_amdgcn_s_barrier();
            asm volatile("" ::: "memory");
        }
        unsigned tmp = bcur; bcur = bnxt; bnxt = bnx2; bnx2 = tmp;
    }

    // epilogue: C row = edge (m), col = out (n)
    #pragma unroll
    for (int mt = 0; mt < 4; ++mt) {
        #pragma unroll
        for (int r = 0; r < 4; ++r) {
            int row = m0 + mt * 16 + lquad * 4 + r;
            int eg  = e_base + row;
            if (eg < NEDGES) {
                float* op = out + (size_t)eg * OUT_DIM + n0 + lrow;
                #pragma unroll
                for (int nt = 0; nt < 4; ++nt)
                    op[nt * 16] = acc[mt][nt][r];
            }
        }
    }
}

// =====================================================================
// FALLBACK (no workspace): round-1 fused kernel, correctness-only
// =====================================================================
#define XSTR 392
#define FSTR 72
#define FOFF_X 0
#define FOFF_A (128 * XSTR)
#define FOFF_B (FOFF_A + 128 * FSTR)
#define FLDS (FOFF_B + OUT_DIM * FSTR)

__global__ __launch_bounds__(512, 2)
void fused_fallback(const float* __restrict__ node_emb,
                    const float* __restrict__ ctx_emb,
                    const int*   __restrict__ pair,
                    const float* __restrict__ ctx_w,
                    const float* __restrict__ ctx_b,
                    const float* __restrict__ base_w,
                    const float* __restrict__ spline_w,
                    const float* __restrict__ spline_s,
                    const float* __restrict__ grid,
                    float* __restrict__ out)
{
    __shared__ unsigned short smem[FLDS];
    const int tid    = threadIdx.x;
    const int e_base = blockIdx.x * 128;
    const int wid    = tid >> 6;
    const int lan    = tid & 63;
    const int lrow   = lan & 15;
    const int lquad  = lan >> 4;

    #pragma unroll
    for (int it = 0; it < 16; ++it) {
        int id    = it * 512 + tid;
        int lane4 = id & 31;
        int e     = (id >> 5) & 127;
        int which = id >> 12;
        int eg = e_base + e; if (eg >= NEDGES) eg = NEDGES - 1;
        int node = pair[eg * 2 + which];
        const float4 v = *(const float4*)(node_emb + (size_t)node * NODE_DIM + lane4 * 4);
        *(ushort4*)&smem[FOFF_X + e * XSTR + which * NODE_DIM + lane4 * 4] =
            make_ushort4(f2bf(v.x), f2bf(v.y), f2bf(v.z), f2bf(v.w));
    }
    {
        f32x4 cacc[4][2];
        #pragma unroll
        for (int a = 0; a < 4; ++a)
            #pragma unroll
            for (int b = 0; b < 2; ++b) { f32x4 z = {0.f,0.f,0.f,0.f}; cacc[a][b] = z; }
        const int m0 = (wid & 1) * 64;
        const int n0 = (wid >> 1) * 32;
        for (int kc = 0; kc < 4; ++kc) {
            #pragma unroll
            for (int it = 0; it < 4; ++it) {
                int id = it * 512 + tid;
                int r  = id >> 4;
                int c4 = id & 15;
                int eg = e_base + r; if (eg >= NEDGES) eg = NEDGES - 1;
                float4 v = *(const float4*)(ctx_emb + (size_t)eg * CTX_DIM + kc * 64 + c4 * 4);
                *(ushort4*)&smem[FOFF_A + r * FSTR + c4 * 4] =
                    make_ushort4(f2bf(v.x), f2bf(v.y), f2bf(v.z), f2bf(v.w));
                float4 w = *(const float4*)(ctx_w + (size_t)r * CTX_DIM + kc * 64 + c4 * 4);
                *(ushort4*)&smem[FOFF_B + r * FSTR + c4 * 4] =
                    make_ushort4(f2bf(w.x), f2bf(w.y), f2bf(w.z), f2bf(w.w));
            }
            __syncthreads();
            #pragma unroll
            for (int ks = 0; ks < 2; ++ks) {
                int koff = ks * 32 + lquad * 8;
                bf16x8 af[4], bfr[2];
                #pragma unroll
                for (int mt = 0; mt < 4; ++mt)
                    af[mt] = *(const bf16x8*)&smem[FOFF_A + (m0 + mt*16 + lrow) * FSTR + koff];
                #pragma unroll
                for (int nt = 0; nt < 2; ++nt)
                    bfr[nt] = *(const bf16x8*)&smem[FOFF_B + (n0 + nt*16 + lrow) * FSTR + koff];
                #pragma unroll
                for (int mt = 0; mt < 4; ++mt)
                    #pragma unroll
                    for (int nt = 0; nt < 2; ++nt)
                        cacc[mt][nt] = __builtin_amdgcn_mfma_f32_16x16x32_bf16(
                            af[mt], bfr[nt], cacc[mt][nt], 0, 0, 0);
            }
            __syncthreads();
        }
        #pragma unroll
        for (int mt = 0; mt < 4; ++mt)
            #pragma unroll
            for (int nt = 0; nt < 2; ++nt)
                #pragma unroll
                for (int r = 0; r < 4; ++r) {
                    int row = m0 + mt*16 + lquad*4 + r;
                    int col = n0 + nt*16 + lrow;
                    smem[FOFF_X + row * XSTR + 256 + col] = f2bf(cacc[mt][nt][r] + ctx_b[col]);
                }
    }
    __syncthreads();

    const float g0   = grid[0];
    const float hinv = 1.0f / (grid[1] - grid[0]);

    f32x4 acc[4][4];
    #pragma unroll
    for (int a = 0; a < 4; ++a)
        #pragma unroll
        for (int b = 0; b < 4; ++b) { f32x4 z = {0.f,0.f,0.f,0.f}; acc[a][b] = z; }

    const int m0 = (wid & 1) * 64;
    const int n0 = (wid >> 1) * 64;

    for (int kb = 0; kb < 48; ++kb) {
        const int seg = kb / 6;
        const int i0  = (kb - seg * 6) * 64;
        #pragma unroll
        for (int it = 0; it < 4; ++it) {
            int id = it * 512 + tid;
            int e  = id >> 4;
            int qq = id & 15;
            ushort4 xv = *(const ushort4*)&smem[FOFF_X + e * XSTR + i0 + qq * 4];
            float x0 = bf2f(xv.x), x1 = bf2f(xv.y), x2 = bf2f(xv.z), x3 = bf2f(xv.w);
            unsigned short r0, r1, r2, r3;
            if (seg == 0) {
                r0 = f2bf(silu(x0)); r1 = f2bf(silu(x1));
                r2 = f2bf(silu(x2)); r3 = f2bf(silu(x3));
            } else {
                const float cf = (float)(seg - 1);
                r0 = f2bf(n3((x0 - g0) * hinv - cf));
                r1 = f2bf(n3((x1 - g0) * hinv - cf));
                r2 = f2bf(n3((x2 - g0) * hinv - cf));
                r3 = f2bf(n3((x3 - g0) * hinv - cf));
            }
            *(ushort4*)&smem[FOFF_A + e * FSTR + qq * 4] = make_ushort4(r0, r1, r2, r3);
        }
        #pragma unroll
        for (int it = 0; it < 4; ++it) {
            int id = it * 512 + tid;
            int o  = id >> 4;
            int qq = id & 15;
            unsigned short r0, r1, r2, r3;
            if (seg == 0) {
                const float4 w = *(const float4*)(base_w + (size_t)o * IN_DIM + i0 + qq * 4);
                r0 = f2bf(w.x); r1 = f2bf(w.y); r2 = f2bf(w.z); r3 = f2bf(w.w);
            } else {
                int c  = seg - 1;
                int bi = o * IN_DIM + i0 + qq * 4;
                r0 = f2bf(spline_w[(size_t)(bi    ) * NCOEF + c] * spline_s[bi    ]);
                r1 = f2bf(spline_w[(size_t)(bi + 1) * NCOEF + c] * spline_s[bi + 1]);
                r2 = f2bf(spline_w[(size_t)(bi + 2) * NCOEF + c] * spline_s[bi + 2]);
                r3 = f2bf(spline_w[(size_t)(bi + 3) * NCOEF + c] * spline_s[bi + 3]);
            }
            *(ushort4*)&smem[FOFF_B + o * FSTR + qq * 4] = make_ushort4(r0, r1, r2, r3);
        }
        __syncthreads();
        #pragma unroll
        for (int ks = 0; ks < 2; ++ks) {
            int koff = ks * 32 + lquad * 8;
            bf16x8 af[4], bfr[4];
            #pragma unroll
            for (int mt = 0; mt < 4; ++mt)
                af[mt] = *(const bf16x8*)&smem[FOFF_A + (m0 + mt*16 + lrow) * FSTR + koff];
            #pragma unroll
            for (int nt = 0; nt < 4; ++nt)
                bfr[nt] = *(const bf16x8*)&smem[FOFF_B + (n0 + nt*16 + lrow) * FSTR + koff];
            #pragma unroll
            for (int mt = 0; mt < 4; ++mt)
                #pragma unroll
                for (int nt = 0; nt < 4; ++nt)
                    acc[mt][nt] = __builtin_amdgcn_mfma_f32_16x16x32_bf16(
                        af[mt], bfr[nt], acc[mt][nt], 0, 0, 0);
        }
        __syncthreads();
    }

    #pragma unroll
    for (int mt = 0; mt < 4; ++mt) {
        #pragma unroll
        for (int r = 0; r < 4; ++r) {
            int row = m0 + mt*16 + lquad*4 + r;
            int eg  = e_base + row;
            if (eg < NEDGES) {
                float* op = out + (size_t)eg * OUT_DIM + n0 + lrow;
                #pragma unroll
                for (int nt = 0; nt < 4; ++nt)
                    op[nt * 16] = acc[mt][nt][r];
            }
        }
    }
}

// ---------------- launch ----------------
extern "C" void kernel_launch(void* const* d_in, const int* in_sizes, int n_in,
                              void* d_out, int out_size, void* d_ws, size_t ws_size,
                              hipStream_t stream)
{
    const float* node_emb = (const float*)d_in[0];
    const float* ctx_emb  = (const float*)d_in[1];
    const int*   pair     = (const int*)d_in[2];
    const float* ctx_w    = (const float*)d_in[3];
    const float* ctx_b    = (const float*)d_in[4];
    const float* base_w   = (const float*)d_in[5];
    const float* spline_w = (const float*)d_in[6];
    const float* spline_s = (const float*)d_in[7];
    const float* grid     = (const float*)d_in[8];
    float* out = (float*)d_out;

    const int nblk = (NEDGES + BM2 - 1) / BM2;     // 782
    const size_t ctxwoff = 1572864u;               // after Wsw (96*256*32*2 B)
    const size_t xoff    = 2u * 1024u * 1024u;     // CtxB
    const size_t need = xoff + (size_t)NEDGES * 128 * sizeof(unsigned short);

    if (ws_size >= need) {
        unsigned short* Wsw   = (unsigned short*)d_ws;
        unsigned short* CtxwB = (unsigned short*)((char*)d_ws + ctxwoff);
        unsigned short* CtxB  = (unsigned short*)((char*)d_ws + xoff);
        prep_w2<<<OUT_DIM, IN_DIM, 0, stream>>>(base_w, spline_w, spline_s, Wsw);
        prep_ctxw<<<128, 64, 0, stream>>>(ctx_w, CtxwB);
        kan_gemm2<<<nblk, THR2, 0, stream>>>(
            Wsw, ctx_emb, CtxwB, ctx_b, CtxB, node_emb, pair, grid, out);
    } else {
        fused_fallback<<<nblk, 512, 0, stream>>>(
            node_emb, ctx_emb, pair, ctx_w, ctx_b, base_w, spline_w, spline_s, grid, out);
    }
}